// Round 3
// baseline (13907.910 us; speedup 1.0000x reference)
//
#include <hip/hip_runtime.h>
#include <hip/hip_bf16.h>

// Problem dims
constexpr int cB = 8, cNQ = 300, cNK = 4096, cE = 256, cH = 8, cD = 32, cF = 2048, cL = 6;
constexpr int MT = cB * cNQ;    // 2400 rows of target stream
constexpr float kScale = 0.17677669529663687f;  // 32^-0.5

// ---------------- copy fp32 ----------------
__global__ void copy_f32(const float* __restrict__ in, float* __restrict__ out, int n) {
  int i = blockIdx.x * 256 + threadIdx.x;
  if (i < n) out[i] = in[i];
}

// ---------------- GEMM: C[M,N] = A[M,K] . W[N,K]^T + bias[N] ----------------
// EPI: 0 = none, 1 = relu
template<int EPI>
__global__ __launch_bounds__(256) void gemm_nt(const float* __restrict__ A,
                                               const float* __restrict__ W,
                                               const float* __restrict__ bias,
                                               float* __restrict__ C,
                                               int M, int N, int K) {
  __shared__ float As[16][65];
  __shared__ float Ws[16][65];
  int tid = threadIdx.x;
  int tm = tid >> 4, tn = tid & 15;
  int bm = blockIdx.x * 64, bn = blockIdx.y * 64;
  float acc[4][4] = {};
  for (int k0 = 0; k0 < K; k0 += 16) {
    for (int i = tid; i < 1024; i += 256) {
      int m = i >> 4, kk = i & 15;
      float v = 0.f;
      if (bm + m < M) v = A[(size_t)(bm + m) * K + k0 + kk];
      As[kk][m] = v;
    }
    for (int i = tid; i < 1024; i += 256) {
      int n = i >> 4, kk = i & 15;
      Ws[kk][n] = W[(size_t)(bn + n) * K + k0 + kk];  // N always multiple of 64
    }
    __syncthreads();
#pragma unroll
    for (int kk = 0; kk < 16; ++kk) {
      float a0[4], w0[4];
#pragma unroll
      for (int i = 0; i < 4; ++i) a0[i] = As[kk][tm * 4 + i];
#pragma unroll
      for (int j = 0; j < 4; ++j) w0[j] = Ws[kk][tn * 4 + j];
#pragma unroll
      for (int i = 0; i < 4; ++i)
#pragma unroll
        for (int j = 0; j < 4; ++j) acc[i][j] += a0[i] * w0[j];
    }
    __syncthreads();
  }
#pragma unroll
  for (int i = 0; i < 4; ++i) {
    int m = bm + tm * 4 + i;
    if (m >= M) continue;
#pragma unroll
    for (int j = 0; j < 4; ++j) {
      int n = bn + tn * 4 + j;
      float v = acc[i][j] + bias[n];
      if (EPI == 1) v = fmaxf(v, 0.f);
      C[(size_t)m * N + n] = v;
    }
  }
}

// ---------------- self-attention (no mask), one wave per (q,h,b) ----------------
// qkv: (2400, 768) with q at col 0, k at 256, v at 512; out: (2400, 256) merged heads
__global__ __launch_bounds__(64) void attn_self_k(const float* __restrict__ qkv, float* __restrict__ out) {
  int q = blockIdx.x, h = blockIdx.y, b = blockIdx.z;
  int lane = threadIdx.x;
  __shared__ float sc[cNQ];
  __shared__ float qv[cD];
  const float* qrow = qkv + ((size_t)(b * cNQ + q)) * 768 + h * cD;
  if (lane < cD) qv[lane] = qrow[lane];
  __syncthreads();
  float lmax = -1e30f;
  for (int k = lane; k < cNQ; k += 64) {
    const float* krow = qkv + ((size_t)(b * cNQ + k)) * 768 + cE + h * cD;
    float s = 0.f;
#pragma unroll
    for (int d = 0; d < cD; ++d) s += qv[d] * krow[d];
    s *= kScale;
    sc[k] = s;
    lmax = fmaxf(lmax, s);
  }
  for (int off = 32; off; off >>= 1) lmax = fmaxf(lmax, __shfl_xor(lmax, off));
  __syncthreads();
  float lsum = 0.f;
  for (int k = lane; k < cNQ; k += 64) {
    float e = __expf(sc[k] - lmax);
    sc[k] = e;
    lsum += e;
  }
  for (int off = 32; off; off >>= 1) lsum += __shfl_xor(lsum, off);
  __syncthreads();
  // output: lanes 0-31 keys [0,150), lanes 32-63 keys [150,300)
  int d = lane & 31, half = lane >> 5;
  float acc = 0.f;
  for (int k = half * 150; k < half * 150 + 150; ++k)
    acc += sc[k] * qkv[((size_t)(b * cNQ + k)) * 768 + 2 * cE + h * cD + d];
  acc += __shfl_down(acc, 32);
  if (lane < 32) out[((size_t)(b * cNQ + q)) * cE + h * cD + d] = acc / lsum;
}

// ---------------- masked cross-attention for ONE batch, 256 threads per (q,h) ----------------
// qb: (300,256) this batch's Q; kb/vb: (4096,256) this batch's K/V; mask: (300,4096) this batch
__global__ __launch_bounds__(256) void attn_cross_k(const float* __restrict__ qb,
                                                    const float* __restrict__ kb,
                                                    const float* __restrict__ vb,
                                                    const int* __restrict__ mask,
                                                    float* __restrict__ out) {
  int q = blockIdx.x, h = blockIdx.y;
  int tid = threadIdx.x;
  __shared__ float sc[cNK];
  __shared__ float qv[cD];
  __shared__ float redmax[4];
  __shared__ float redsum[4];
  __shared__ float pacc[8][cD];
  if (tid < cD) qv[tid] = qb[(size_t)q * cE + h * cD + tid];
  __syncthreads();
  const int* mrow = mask + (size_t)q * cNK;
  float lmax = -1e30f;
  for (int k = tid; k < cNK; k += 256) {
    float s = -1e30f;
    if (mrow[k]) {
      const float* krow = kb + (size_t)k * cE + h * cD;
      s = 0.f;
#pragma unroll
      for (int d = 0; d < cD; ++d) s += qv[d] * krow[d];
      s *= kScale;
    }
    sc[k] = s;
    lmax = fmaxf(lmax, s);
  }
  for (int off = 32; off; off >>= 1) lmax = fmaxf(lmax, __shfl_xor(lmax, off));
  if ((tid & 63) == 0) redmax[tid >> 6] = lmax;
  __syncthreads();
  float m = fmaxf(fmaxf(redmax[0], redmax[1]), fmaxf(redmax[2], redmax[3]));
  float lsum = 0.f;
  for (int k = tid; k < cNK; k += 256) {
    float e = __expf(sc[k] - m);
    sc[k] = e;
    lsum += e;
  }
  for (int off = 32; off; off >>= 1) lsum += __shfl_xor(lsum, off);
  if ((tid & 63) == 0) redsum[tid >> 6] = lsum;
  __syncthreads();
  float total = redsum[0] + redsum[1] + redsum[2] + redsum[3];
  // output: 8 groups of 32 lanes; group g sums keys [g*512,(g+1)*512), lane d holds dim d
  int d = tid & 31, g = tid >> 5;
  float acc = 0.f;
  for (int k = g * 512; k < g * 512 + 512; ++k)
    acc += sc[k] * vb[(size_t)k * cE + h * cD + d];
  pacc[g][d] = acc;
  __syncthreads();
  if (tid < 32) {
    float o = 0.f;
#pragma unroll
    for (int gg = 0; gg < 8; ++gg) o += pacc[gg][d];
    out[(size_t)q * cE + h * cD + d] = o / total;
  }
}

// ---------------- residual + LayerNorm (in-place on t), one wave per row ----------------
__global__ __launch_bounds__(64) void add_ln_k(float* __restrict__ t, const float* __restrict__ delta,
                                               const float* __restrict__ g,
                                               const float* __restrict__ bb) {
  int r = blockIdx.x, lane = threadIdx.x;
  size_t base = (size_t)r * cE + lane * 4;
  float x[4];
  float s = 0.f;
#pragma unroll
  for (int i = 0; i < 4; ++i) { x[i] = t[base + i] + delta[base + i]; s += x[i]; }
  for (int off = 32; off; off >>= 1) s += __shfl_xor(s, off);
  float mean = s * (1.f / cE);
  float v = 0.f;
#pragma unroll
  for (int i = 0; i < 4; ++i) { float dd = x[i] - mean; v += dd * dd; }
  for (int off = 32; off; off >>= 1) v += __shfl_xor(v, off);
  float rstd = rsqrtf(v * (1.f / cE) + 1e-5f);
#pragma unroll
  for (int i = 0; i < 4; ++i)
    t[base + i] = (x[i] - mean) * rstd * g[lane * 4 + i] + bb[lane * 4 + i];
}

// ---------------- final LayerNorm -> fp32 out ----------------
__global__ __launch_bounds__(64) void final_ln_k(const float* __restrict__ t,
                                                 const float* __restrict__ g,
                                                 const float* __restrict__ bb,
                                                 float* __restrict__ out) {
  int r = blockIdx.x, lane = threadIdx.x;
  size_t base = (size_t)r * cE + lane * 4;
  float x[4];
  float s = 0.f;
#pragma unroll
  for (int i = 0; i < 4; ++i) { x[i] = t[base + i]; s += x[i]; }
  for (int off = 32; off; off >>= 1) s += __shfl_xor(s, off);
  float mean = s * (1.f / cE);
  float v = 0.f;
#pragma unroll
  for (int i = 0; i < 4; ++i) { float dd = x[i] - mean; v += dd * dd; }
  for (int off = 32; off; off >>= 1) v += __shfl_xor(v, off);
  float rstd = rsqrtf(v * (1.f / cE) + 1e-5f);
#pragma unroll
  for (int i = 0; i < 4; ++i)
    out[base + i] = (x[i] - mean) * rstd * g[lane * 4 + i] + bb[lane * 4 + i];
}

extern "C" void kernel_launch(void* const* d_in, const int* in_sizes, int n_in,
                              void* d_out, int out_size, void* d_ws, size_t ws_size,
                              hipStream_t stream) {
  (void)in_sizes; (void)n_in; (void)out_size; (void)ws_size;
  const float* tgt    = (const float*)d_in[0];
  const float* memory = (const float*)d_in[1];
  const int*   gmask  = (const int*)d_in[2];
  const float* sa_wqkv = (const float*)d_in[3];
  const float* sa_bqkv = (const float*)d_in[4];
  const float* sa_wo   = (const float*)d_in[5];
  const float* sa_bo   = (const float*)d_in[6];
  const float* ca_wq   = (const float*)d_in[7];
  const float* ca_bq   = (const float*)d_in[8];
  const float* ca_wk   = (const float*)d_in[9];
  const float* ca_bk   = (const float*)d_in[10];
  const float* ca_wv   = (const float*)d_in[11];
  const float* ca_bv   = (const float*)d_in[12];
  const float* ca_wo   = (const float*)d_in[13];
  const float* ca_bo   = (const float*)d_in[14];
  const float* f_w1    = (const float*)d_in[15];
  const float* f_b1    = (const float*)d_in[16];
  const float* f_w2    = (const float*)d_in[17];
  const float* f_b2    = (const float*)d_in[18];
  const float* ln1g    = (const float*)d_in[19];
  const float* ln1b    = (const float*)d_in[20];
  const float* ln2g    = (const float*)d_in[21];
  const float* ln2b    = (const float*)d_in[22];
  const float* ln3g    = (const float*)d_in[23];
  const float* ln3b    = (const float*)d_in[24];
  const float* lnfg    = (const float*)d_in[25];
  const float* lnfb    = (const float*)d_in[26];

  // workspace layout (fp32) — total 8,855,552 floats = 33.8 MiB
  float* t    = (float*)d_ws;                  // 2400*256
  float* s1   = t    + (size_t)MT * cE;        // 2400*256
  float* s2   = s1   + (size_t)MT * cE;        // 2400*256
  float* big  = s2   + (size_t)MT * cE;        // 2400*2048 (qkv 2400x768 / ffn hidden)
  float* kbuf = big  + (size_t)MT * cF;        // 4096*256 (per-batch K)
  float* vbuf = kbuf + (size_t)cNK * cE;       // 4096*256 (per-batch V)

  // t = copy(tgt)
  copy_f32<<<(MT * cE + 255) / 256, 256, 0, stream>>>(tgt, t, MT * cE);

  for (int l = 0; l < cL; ++l) {
    const float* wqkv = sa_wqkv + (size_t)l * 3 * cE * cE;
    const float* bqkv = sa_bqkv + (size_t)l * 3 * cE;
    const float* wo   = sa_wo   + (size_t)l * cE * cE;
    const float* bo   = sa_bo   + (size_t)l * cE;
    const float* wq   = ca_wq   + (size_t)l * cE * cE;
    const float* bq   = ca_bq   + (size_t)l * cE;
    const float* wk   = ca_wk   + (size_t)l * cE * cE;
    const float* bk   = ca_bk   + (size_t)l * cE;
    const float* wv   = ca_wv   + (size_t)l * cE * cE;
    const float* bv   = ca_bv   + (size_t)l * cE;
    const float* wco  = ca_wo   + (size_t)l * cE * cE;
    const float* bco  = ca_bo   + (size_t)l * cE;
    const float* w1   = f_w1    + (size_t)l * cF * cE;
    const float* b1   = f_b1    + (size_t)l * cF;
    const float* w2   = f_w2    + (size_t)l * cE * cF;
    const float* b2   = f_b2    + (size_t)l * cE;

    // 1) qkv = t @ wqkv^T + bqkv    (2400 x 768) -> big
    gemm_nt<0><<<dim3(38, 12), 256, 0, stream>>>(t, wqkv, bqkv, big, MT, 3 * cE, cE);
    // 2) self attention -> s1 (2400 x 256)
    attn_self_k<<<dim3(cNQ, cH, cB), 64, 0, stream>>>(big, s1);
    // 3) sa out proj -> s2
    gemm_nt<0><<<dim3(38, 4), 256, 0, stream>>>(s1, wo, bo, s2, MT, cE, cE);
    // 4) t = LN(t + s2)
    add_ln_k<<<MT, 64, 0, stream>>>(t, s2, ln1g + (size_t)l * cE, ln1b + (size_t)l * cE);
    // 5) q = t @ wq^T + bq -> s1
    gemm_nt<0><<<dim3(38, 4), 256, 0, stream>>>(t, wq, bq, s1, MT, cE, cE);
    // 6-8) per-batch: K/V projection + masked cross attention -> s2
    for (int b = 0; b < cB; ++b) {
      const float* memb = memory + (size_t)b * cNK * cE;
      gemm_nt<0><<<dim3(64, 4), 256, 0, stream>>>(memb, wk, bk, kbuf, cNK, cE, cE);
      gemm_nt<0><<<dim3(64, 4), 256, 0, stream>>>(memb, wv, bv, vbuf, cNK, cE, cE);
      attn_cross_k<<<dim3(cNQ, cH), 256, 0, stream>>>(
          s1 + (size_t)b * cNQ * cE, kbuf, vbuf,
          gmask + (size_t)b * cNQ * cNK, s2 + (size_t)b * cNQ * cE);
    }
    // 9) ca out proj -> s1
    gemm_nt<0><<<dim3(38, 4), 256, 0, stream>>>(s2, wco, bco, s1, MT, cE, cE);
    // 10) t = LN(t + s1)
    add_ln_k<<<MT, 64, 0, stream>>>(t, s1, ln2g + (size_t)l * cE, ln2b + (size_t)l * cE);
    // 11) hidden = relu(t @ w1^T + b1) -> big (2400 x 2048)
    gemm_nt<1><<<dim3(38, 32), 256, 0, stream>>>(t, w1, b1, big, MT, cF, cE);
    // 12) f = hidden @ w2^T + b2 -> s1
    gemm_nt<0><<<dim3(38, 4), 256, 0, stream>>>(big, w2, b2, s1, MT, cE, cF);
    // 13) t = LN(t + s1)
    add_ln_k<<<MT, 64, 0, stream>>>(t, s1, ln3g + (size_t)l * cE, ln3b + (size_t)l * cE);
  }

  // final LN -> fp32 out
  final_ln_k<<<MT, 64, 0, stream>>>(t, lnfg, lnfb, (float*)d_out);
}

// Round 4
// 7442.050 us; speedup vs baseline: 1.8688x; 1.8688x over previous
//
#include <hip/hip_runtime.h>
#include <hip/hip_bf16.h>

// Problem dims
constexpr int cB = 8, cNQ = 300, cNK = 4096, cE = 256, cH = 8, cD = 32, cF = 2048, cL = 6;
constexpr int MT = cB * cNQ;    // 2400 rows of target stream
constexpr float kScale = 0.17677669529663687f;  // 32^-0.5

typedef __attribute__((ext_vector_type(8))) short short8_t;   // 8 bf16 in 4 VGPRs
typedef __attribute__((ext_vector_type(4))) float float4_t;

__device__ inline short f2bf(float x) {
  __hip_bfloat16 h = __float2bfloat16(x);
  return __builtin_bit_cast(short, h);
}

// ---------------- copy fp32 ----------------
__global__ void copy_f32(const float* __restrict__ in, float* __restrict__ out, int n) {
  int i = blockIdx.x * 256 + threadIdx.x;
  if (i < n) out[i] = in[i];
}

// ---------------- MFMA GEMM: C[M,N] = A[M,K]fp32 . W[N,K]fp32^T + bias[N] ----------------
// bf16 inputs (cast in staging), fp32 accumulate. EPI: 0=none, 1=relu. TOUT: float or bf16.
// Tile 64x64, BK=64, 256 threads = 4 waves, each wave 32x32 via 2x2 mfma_16x16x32.
// Requires: N % 64 == 0, K % 64 == 0. M arbitrary (guarded).
template<int EPI, typename TOUT>
__global__ __launch_bounds__(256) void gemm_mfma(const float* __restrict__ A,
                                                 const float* __restrict__ W,
                                                 const float* __restrict__ bias,
                                                 TOUT* __restrict__ C,
                                                 int M, int N, int K) {
  constexpr int LDSS = 72;  // 64 + 8 bf16 pad; 144 B row stride, 16B aligned
  __shared__ short As[64][LDSS];
  __shared__ short Ws[64][LDSS];
  int tid = threadIdx.x;
  int bm = blockIdx.x * 64, bn = blockIdx.y * 64;
  int lane = tid & 63, wave = tid >> 6;
  int m16 = lane & 15, quad = lane >> 4;
  int wm = (wave >> 1) * 32, wn = (wave & 1) * 32;

  // staging assignment: row = tid>>2 (0..63), 16 consecutive k at kc=(tid&3)*16
  int srow = tid >> 2;
  int kc = (tid & 3) * 16;
  bool aok = (bm + srow) < M;

  float4_t acc[2][2];
#pragma unroll
  for (int i = 0; i < 2; ++i)
#pragma unroll
    for (int j = 0; j < 2; ++j) acc[i][j] = (float4_t){0.f, 0.f, 0.f, 0.f};

  for (int k0 = 0; k0 < K; k0 += 64) {
    // ---- stage A ----
    {
      const float* src = A + (size_t)(bm + srow) * K + k0 + kc;
      short8_t p0, p1;
#pragma unroll
      for (int u = 0; u < 8; ++u) p0[u] = aok ? f2bf(src[u]) : (short)0;
#pragma unroll
      for (int u = 0; u < 8; ++u) p1[u] = aok ? f2bf(src[8 + u]) : (short)0;
      *(short8_t*)&As[srow][kc] = p0;
      *(short8_t*)&As[srow][kc + 8] = p1;
    }
    // ---- stage W (always in bounds: N multiple of 64) ----
    {
      const float* src = W + (size_t)(bn + srow) * K + k0 + kc;
      short8_t p0, p1;
#pragma unroll
      for (int u = 0; u < 8; ++u) p0[u] = f2bf(src[u]);
#pragma unroll
      for (int u = 0; u < 8; ++u) p1[u] = f2bf(src[8 + u]);
      *(short8_t*)&Ws[srow][kc] = p0;
      *(short8_t*)&Ws[srow][kc + 8] = p1;
    }
    __syncthreads();
#pragma unroll
    for (int kk = 0; kk < 2; ++kk) {
      short8_t aF[2], bF[2];
#pragma unroll
      for (int i = 0; i < 2; ++i)
        aF[i] = *(const short8_t*)&As[wm + i * 16 + m16][kk * 32 + quad * 8];
#pragma unroll
      for (int j = 0; j < 2; ++j)
        bF[j] = *(const short8_t*)&Ws[wn + j * 16 + m16][kk * 32 + quad * 8];
#pragma unroll
      for (int i = 0; i < 2; ++i)
#pragma unroll
        for (int j = 0; j < 2; ++j)
          acc[i][j] = __builtin_amdgcn_mfma_f32_16x16x32_bf16(aF[i], bF[j], acc[i][j], 0, 0, 0);
    }
    __syncthreads();
  }

  // epilogue: C/D layout col=lane&15, row=quad*4+reg
#pragma unroll
  for (int i = 0; i < 2; ++i) {
#pragma unroll
    for (int r = 0; r < 4; ++r) {
      int m = bm + wm + i * 16 + quad * 4 + r;
      if (m >= M) continue;
#pragma unroll
      for (int j = 0; j < 2; ++j) {
        int n = bn + wn + j * 16 + m16;
        float v = acc[i][j][r] + bias[n];
        if (EPI == 1) v = fmaxf(v, 0.f);
        if constexpr (__hip_internal::is_same<TOUT, float>::value)
          C[(size_t)m * N + n] = v;
        else
          C[(size_t)m * N + n] = __float2bfloat16(v);
      }
    }
  }
}

// ---------------- self-attention (no mask), one wave per (q,h,b) ----------------
// qkv: (2400, 768) with q at col 0, k at 256, v at 512; out: (2400, 256) merged heads
__global__ __launch_bounds__(64) void attn_self_k(const float* __restrict__ qkv, float* __restrict__ out) {
  int q = blockIdx.x, h = blockIdx.y, b = blockIdx.z;
  int lane = threadIdx.x;
  __shared__ float sc[cNQ];
  __shared__ float qv[cD];
  const float* qrow = qkv + ((size_t)(b * cNQ + q)) * 768 + h * cD;
  if (lane < cD) qv[lane] = qrow[lane];
  __syncthreads();
  float lmax = -1e30f;
  for (int k = lane; k < cNQ; k += 64) {
    const float* krow = qkv + ((size_t)(b * cNQ + k)) * 768 + cE + h * cD;
    float s = 0.f;
#pragma unroll
    for (int d = 0; d < cD; ++d) s += qv[d] * krow[d];
    s *= kScale;
    sc[k] = s;
    lmax = fmaxf(lmax, s);
  }
  for (int off = 32; off; off >>= 1) lmax = fmaxf(lmax, __shfl_xor(lmax, off));
  __syncthreads();
  float lsum = 0.f;
  for (int k = lane; k < cNQ; k += 64) {
    float e = __expf(sc[k] - lmax);
    sc[k] = e;
    lsum += e;
  }
  for (int off = 32; off; off >>= 1) lsum += __shfl_xor(lsum, off);
  __syncthreads();
  int d = lane & 31, half = lane >> 5;
  float acc = 0.f;
  for (int k = half * 150; k < half * 150 + 150; ++k)
    acc += sc[k] * qkv[((size_t)(b * cNQ + k)) * 768 + 2 * cE + h * cD + d];
  acc += __shfl_down(acc, 32);
  if (lane < 32) out[((size_t)(b * cNQ + q)) * cE + h * cD + d] = acc / lsum;
}

// ---------------- masked cross-attention for ONE batch, 256 threads per (q,h) ----------------
// qb: (300,256) fp32 Q; kb/vb: (4096,256) bf16 K/V; mask: (300,4096) this batch
__global__ __launch_bounds__(256) void attn_cross_k(const float* __restrict__ qb,
                                                    const __hip_bfloat16* __restrict__ kb,
                                                    const __hip_bfloat16* __restrict__ vb,
                                                    const int* __restrict__ mask,
                                                    float* __restrict__ out) {
  int q = blockIdx.x, h = blockIdx.y;
  int tid = threadIdx.x;
  __shared__ float sc[cNK];
  __shared__ float qv[cD];
  __shared__ float redmax[4];
  __shared__ float redsum[4];
  __shared__ float pacc[8][cD];
  if (tid < cD) qv[tid] = qb[(size_t)q * cE + h * cD + tid];
  __syncthreads();
  const int* mrow = mask + (size_t)q * cNK;
  float lmax = -1e30f;
  for (int k = tid; k < cNK; k += 256) {
    float s = -1e30f;
    if (mrow[k]) {
      const __hip_bfloat16* krow = kb + (size_t)k * cE + h * cD;
      s = 0.f;
#pragma unroll
      for (int d = 0; d < cD; ++d) s += qv[d] * (float)krow[d];
      s *= kScale;
    }
    sc[k] = s;
    lmax = fmaxf(lmax, s);
  }
  for (int off = 32; off; off >>= 1) lmax = fmaxf(lmax, __shfl_xor(lmax, off));
  if ((tid & 63) == 0) redmax[tid >> 6] = lmax;
  __syncthreads();
  float m = fmaxf(fmaxf(redmax[0], redmax[1]), fmaxf(redmax[2], redmax[3]));
  float lsum = 0.f;
  for (int k = tid; k < cNK; k += 256) {
    float e = __expf(sc[k] - m);
    sc[k] = e;
    lsum += e;
  }
  for (int off = 32; off; off >>= 1) lsum += __shfl_xor(lsum, off);
  if ((tid & 63) == 0) redsum[tid >> 6] = lsum;
  __syncthreads();
  float total = redsum[0] + redsum[1] + redsum[2] + redsum[3];
  int d = tid & 31, g = tid >> 5;
  float acc = 0.f;
  for (int k = g * 512; k < g * 512 + 512; ++k)
    acc += sc[k] * (float)vb[(size_t)k * cE + h * cD + d];
  pacc[g][d] = acc;
  __syncthreads();
  if (tid < 32) {
    float o = 0.f;
#pragma unroll
    for (int gg = 0; gg < 8; ++gg) o += pacc[gg][d];
    out[(size_t)q * cE + h * cD + d] = o / total;
  }
}

// ---------------- residual + LayerNorm (in-place on t), one wave per row ----------------
__global__ __launch_bounds__(64) void add_ln_k(float* __restrict__ t, const float* __restrict__ delta,
                                               const float* __restrict__ g,
                                               const float* __restrict__ bb) {
  int r = blockIdx.x, lane = threadIdx.x;
  size_t base = (size_t)r * cE + lane * 4;
  float x[4];
  float s = 0.f;
#pragma unroll
  for (int i = 0; i < 4; ++i) { x[i] = t[base + i] + delta[base + i]; s += x[i]; }
  for (int off = 32; off; off >>= 1) s += __shfl_xor(s, off);
  float mean = s * (1.f / cE);
  float v = 0.f;
#pragma unroll
  for (int i = 0; i < 4; ++i) { float dd = x[i] - mean; v += dd * dd; }
  for (int off = 32; off; off >>= 1) v += __shfl_xor(v, off);
  float rstd = rsqrtf(v * (1.f / cE) + 1e-5f);
#pragma unroll
  for (int i = 0; i < 4; ++i)
    t[base + i] = (x[i] - mean) * rstd * g[lane * 4 + i] + bb[lane * 4 + i];
}

// ---------------- final LayerNorm -> fp32 out ----------------
__global__ __launch_bounds__(64) void final_ln_k(const float* __restrict__ t,
                                                 const float* __restrict__ g,
                                                 const float* __restrict__ bb,
                                                 float* __restrict__ out) {
  int r = blockIdx.x, lane = threadIdx.x;
  size_t base = (size_t)r * cE + lane * 4;
  float x[4];
  float s = 0.f;
#pragma unroll
  for (int i = 0; i < 4; ++i) { x[i] = t[base + i]; s += x[i]; }
  for (int off = 32; off; off >>= 1) s += __shfl_xor(s, off);
  float mean = s * (1.f / cE);
  float v = 0.f;
#pragma unroll
  for (int i = 0; i < 4; ++i) { float dd = x[i] - mean; v += dd * dd; }
  for (int off = 32; off; off >>= 1) v += __shfl_xor(v, off);
  float rstd = rsqrtf(v * (1.f / cE) + 1e-5f);
#pragma unroll
  for (int i = 0; i < 4; ++i)
    out[base + i] = (x[i] - mean) * rstd * g[lane * 4 + i] + bb[lane * 4 + i];
}

extern "C" void kernel_launch(void* const* d_in, const int* in_sizes, int n_in,
                              void* d_out, int out_size, void* d_ws, size_t ws_size,
                              hipStream_t stream) {
  (void)in_sizes; (void)n_in; (void)out_size; (void)ws_size;
  const float* tgt    = (const float*)d_in[0];
  const float* memory = (const float*)d_in[1];
  const int*   gmask  = (const int*)d_in[2];
  const float* sa_wqkv = (const float*)d_in[3];
  const float* sa_bqkv = (const float*)d_in[4];
  const float* sa_wo   = (const float*)d_in[5];
  const float* sa_bo   = (const float*)d_in[6];
  const float* ca_wq   = (const float*)d_in[7];
  const float* ca_bq   = (const float*)d_in[8];
  const float* ca_wk   = (const float*)d_in[9];
  const float* ca_bk   = (const float*)d_in[10];
  const float* ca_wv   = (const float*)d_in[11];
  const float* ca_bv   = (const float*)d_in[12];
  const float* ca_wo   = (const float*)d_in[13];
  const float* ca_bo   = (const float*)d_in[14];
  const float* f_w1    = (const float*)d_in[15];
  const float* f_b1    = (const float*)d_in[16];
  const float* f_w2    = (const float*)d_in[17];
  const float* f_b2    = (const float*)d_in[18];
  const float* ln1g    = (const float*)d_in[19];
  const float* ln1b    = (const float*)d_in[20];
  const float* ln2g    = (const float*)d_in[21];
  const float* ln2b    = (const float*)d_in[22];
  const float* ln3g    = (const float*)d_in[23];
  const float* ln3b    = (const float*)d_in[24];
  const float* lnfg    = (const float*)d_in[25];
  const float* lnfb    = (const float*)d_in[26];

  // workspace layout — fp32 bufs + bf16 K/V; total ~29.5 MiB
  float* t    = (float*)d_ws;                  // 2400*256
  float* s1   = t    + (size_t)MT * cE;        // 2400*256
  float* s2   = s1   + (size_t)MT * cE;        // 2400*256
  float* big  = s2   + (size_t)MT * cE;        // 2400*2048 (qkv 2400x768 / ffn hidden)
  __hip_bfloat16* kbuf = (__hip_bfloat16*)(big + (size_t)MT * cF);  // 4096*256 bf16
  __hip_bfloat16* vbuf = kbuf + (size_t)cNK * cE;                   // 4096*256 bf16

  copy_f32<<<(MT * cE + 255) / 256, 256, 0, stream>>>(tgt, t, MT * cE);

  for (int l = 0; l < cL; ++l) {
    const float* wqkv = sa_wqkv + (size_t)l * 3 * cE * cE;
    const float* bqkv = sa_bqkv + (size_t)l * 3 * cE;
    const float* wo   = sa_wo   + (size_t)l * cE * cE;
    const float* bo   = sa_bo   + (size_t)l * cE;
    const float* wq   = ca_wq   + (size_t)l * cE * cE;
    const float* bq   = ca_bq   + (size_t)l * cE;
    const float* wk   = ca_wk   + (size_t)l * cE * cE;
    const float* bk   = ca_bk   + (size_t)l * cE;
    const float* wv   = ca_wv   + (size_t)l * cE * cE;
    const float* bv   = ca_bv   + (size_t)l * cE;
    const float* wco  = ca_wo   + (size_t)l * cE * cE;
    const float* bco  = ca_bo   + (size_t)l * cE;
    const float* w1   = f_w1    + (size_t)l * cF * cE;
    const float* b1   = f_b1    + (size_t)l * cF;
    const float* w2   = f_w2    + (size_t)l * cE * cF;
    const float* b2   = f_b2    + (size_t)l * cE;

    // 1) qkv = t @ wqkv^T + bqkv  (2400 x 768) -> big
    gemm_mfma<0, float><<<dim3(38, 12), 256, 0, stream>>>(t, wqkv, bqkv, big, MT, 3 * cE, cE);
    // 2) self attention -> s1
    attn_self_k<<<dim3(cNQ, cH, cB), 64, 0, stream>>>(big, s1);
    // 3) sa out proj -> s2
    gemm_mfma<0, float><<<dim3(38, 4), 256, 0, stream>>>(s1, wo, bo, s2, MT, cE, cE);
    // 4) t = LN(t + s2)
    add_ln_k<<<MT, 64, 0, stream>>>(t, s2, ln1g + (size_t)l * cE, ln1b + (size_t)l * cE);
    // 5) q = t @ wq^T + bq -> s1
    gemm_mfma<0, float><<<dim3(38, 4), 256, 0, stream>>>(t, wq, bq, s1, MT, cE, cE);
    // 6-8) per-batch: K/V projection (bf16 out) + masked cross attention -> s2
    for (int b = 0; b < cB; ++b) {
      const float* memb = memory + (size_t)b * cNK * cE;
      gemm_mfma<0, __hip_bfloat16><<<dim3(64, 4), 256, 0, stream>>>(memb, wk, bk, kbuf, cNK, cE, cE);
      gemm_mfma<0, __hip_bfloat16><<<dim3(64, 4), 256, 0, stream>>>(memb, wv, bv, vbuf, cNK, cE, cE);
      attn_cross_k<<<dim3(cNQ, cH), 256, 0, stream>>>(
          s1 + (size_t)b * cNQ * cE, kbuf, vbuf,
          gmask + (size_t)b * cNQ * cNK, s2 + (size_t)b * cNQ * cE);
    }
    // 9) ca out proj -> s1
    gemm_mfma<0, float><<<dim3(38, 4), 256, 0, stream>>>(s2, wco, bco, s1, MT, cE, cE);
    // 10) t = LN(t + s1)
    add_ln_k<<<MT, 64, 0, stream>>>(t, s1, ln2g + (size_t)l * cE, ln2b + (size_t)l * cE);
    // 11) hidden = relu(t @ w1^T + b1) -> big (2400 x 2048)
    gemm_mfma<1, float><<<dim3(38, 32), 256, 0, stream>>>(t, w1, b1, big, MT, cF, cE);
    // 12) f = hidden @ w2^T + b2 -> s1
    gemm_mfma<0, float><<<dim3(38, 4), 256, 0, stream>>>(big, w2, b2, s1, MT, cE, cF);
    // 13) t = LN(t + s1)
    add_ln_k<<<MT, 64, 0, stream>>>(t, s1, ln3g + (size_t)l * cE, ln3b + (size_t)l * cE);
  }

  final_ln_k<<<MT, 64, 0, stream>>>(t, lnfg, lnfb, (float*)d_out);
}

// Round 6
// 3007.033 us; speedup vs baseline: 4.6251x; 2.4749x over previous
//
#include <hip/hip_runtime.h>
#include <hip/hip_bf16.h>

// Problem dims
constexpr int cB = 8, cNQ = 300, cNK = 4096, cE = 256, cH = 8, cD = 32, cF = 2048, cL = 6;
constexpr int MT = cB * cNQ;    // 2400 rows of target stream
constexpr int MM = cB * cNK;    // 32768 rows of memory stream
constexpr float kScale = 0.17677669529663687f;  // 32^-0.5

typedef __attribute__((ext_vector_type(8))) short short8_t;   // 8 bf16 in 4 VGPRs
typedef __attribute__((ext_vector_type(4))) short short4_t;   // 8B
typedef __attribute__((ext_vector_type(4))) float float4_t;

__device__ inline short f2bf(float x) {
  __hip_bfloat16 h = __float2bfloat16(x);
  return __builtin_bit_cast(short, h);
}
__device__ inline float bf2f(short s) {
  return (float)__builtin_bit_cast(__hip_bfloat16, s);
}

// ---------------- copy fp32 ----------------
__global__ void copy_f32(const float* __restrict__ in, float* __restrict__ out, int n) {
  int i = blockIdx.x * 256 + threadIdx.x;
  if (i < n) out[i] = in[i];
}

// ---------------- pack geometry mask into bits (one-time) ----------------
// m: 2400*4096 ints; bits: 2400*128 words. n divisible by 64.
__global__ void pack_mask(const int* __restrict__ m, unsigned* __restrict__ bits, int n) {
  int i = blockIdx.x * 256 + threadIdx.x;
  bool on = (i < n) && (m[i] != 0);
  unsigned long long bal = __ballot(on);
  int lane = threadIdx.x & 63;
  int base = (blockIdx.x * 256 + (threadIdx.x & ~63)) >> 5;  // word idx of lane 0
  if (lane == 0)  bits[base]     = (unsigned)bal;
  if (lane == 32) bits[base + 1] = (unsigned)(bal >> 32);
}

// ---------------- MFMA GEMM: C[M,N] = A[M,K] . W[N,K]^T + bias[N] ----------------
// TA: float (cast to bf16 in staging) or __hip_bfloat16 (direct). W fp32. fp32 accumulate.
// EPI: 0=none, 1=relu. TOUT: float or __hip_bfloat16.
// Tile 64x64, BK=64, 256 threads = 4 waves, each wave 32x32 via 2x2 mfma_16x16x32.
// Requires: N % 64 == 0, K % 64 == 0. M arbitrary (guarded).
template<typename TA, int EPI, typename TOUT>
__global__ __launch_bounds__(256) void gemm_mfma(const TA* __restrict__ A,
                                                 const float* __restrict__ W,
                                                 const float* __restrict__ bias,
                                                 TOUT* __restrict__ C,
                                                 int M, int N, int K) {
  constexpr int LDSS = 72;  // 64 + 8 bf16 pad
  __shared__ short As[64][LDSS];
  __shared__ short Ws[64][LDSS];
  int tid = threadIdx.x;
  int bm = blockIdx.x * 64, bn = blockIdx.y * 64;
  int lane = tid & 63, wave = tid >> 6;
  int m16 = lane & 15, quad = lane >> 4;
  int wm = (wave >> 1) * 32, wn = (wave & 1) * 32;

  int srow = tid >> 2;
  int kc = (tid & 3) * 16;
  bool aok = (bm + srow) < M;

  float4_t acc[2][2];
#pragma unroll
  for (int i = 0; i < 2; ++i)
#pragma unroll
    for (int j = 0; j < 2; ++j) acc[i][j] = (float4_t){0.f, 0.f, 0.f, 0.f};

  for (int k0 = 0; k0 < K; k0 += 64) {
    // ---- stage A ----
    if constexpr (__hip_internal::is_same<TA, float>::value) {
      const float* src = A + (size_t)(bm + srow) * K + k0 + kc;
      short8_t p0, p1;
#pragma unroll
      for (int u = 0; u < 8; ++u) p0[u] = aok ? f2bf(src[u]) : (short)0;
#pragma unroll
      for (int u = 0; u < 8; ++u) p1[u] = aok ? f2bf(src[8 + u]) : (short)0;
      *(short8_t*)&As[srow][kc] = p0;
      *(short8_t*)&As[srow][kc + 8] = p1;
    } else {
      const TA* src = A + (size_t)(bm + srow) * K + k0 + kc;
      short8_t z = 0;
      short8_t p0 = aok ? *(const short8_t*)src : z;
      short8_t p1 = aok ? *(const short8_t*)(src + 8) : z;
      *(short8_t*)&As[srow][kc] = p0;
      *(short8_t*)&As[srow][kc + 8] = p1;
    }
    // ---- stage W (always in bounds: N multiple of 64) ----
    {
      const float* src = W + (size_t)(bn + srow) * K + k0 + kc;
      short8_t p0, p1;
#pragma unroll
      for (int u = 0; u < 8; ++u) p0[u] = f2bf(src[u]);
#pragma unroll
      for (int u = 0; u < 8; ++u) p1[u] = f2bf(src[8 + u]);
      *(short8_t*)&Ws[srow][kc] = p0;
      *(short8_t*)&Ws[srow][kc + 8] = p1;
    }
    __syncthreads();
#pragma unroll
    for (int kk = 0; kk < 2; ++kk) {
      short8_t aF[2], bF[2];
#pragma unroll
      for (int i = 0; i < 2; ++i)
        aF[i] = *(const short8_t*)&As[wm + i * 16 + m16][kk * 32 + quad * 8];
#pragma unroll
      for (int j = 0; j < 2; ++j)
        bF[j] = *(const short8_t*)&Ws[wn + j * 16 + m16][kk * 32 + quad * 8];
#pragma unroll
      for (int i = 0; i < 2; ++i)
#pragma unroll
        for (int j = 0; j < 2; ++j)
          acc[i][j] = __builtin_amdgcn_mfma_f32_16x16x32_bf16(aF[i], bF[j], acc[i][j], 0, 0, 0);
    }
    __syncthreads();
  }

  // epilogue: C/D layout col=lane&15, row=quad*4+reg
#pragma unroll
  for (int i = 0; i < 2; ++i) {
#pragma unroll
    for (int r = 0; r < 4; ++r) {
      int m = bm + wm + i * 16 + quad * 4 + r;
      if (m >= M) continue;
#pragma unroll
      for (int j = 0; j < 2; ++j) {
        int n = bn + wn + j * 16 + m16;
        float v = acc[i][j][r] + bias[n];
        if (EPI == 1) v = fmaxf(v, 0.f);
        if constexpr (__hip_internal::is_same<TOUT, float>::value)
          C[(size_t)m * N + n] = v;
        else
          C[(size_t)m * N + n] = __float2bfloat16(v);
      }
    }
  }
}

// ---------------- self-attention (no mask), one wave per (q,h,b) ----------------
// qkv: (2400, 768) bf16, q at 0, k at 256, v at 512; out: (2400,256) fp32 merged heads
__global__ __launch_bounds__(64) void attn_self_k(const __hip_bfloat16* __restrict__ qkv,
                                                  float* __restrict__ out) {
  int q = blockIdx.x, h = blockIdx.y, b = blockIdx.z;
  int lane = threadIdx.x;
  __shared__ float sc[cNQ];
  __shared__ float qv[cD];
  if (lane < cD) qv[lane] = bf2f(__builtin_bit_cast(short, qkv[((size_t)(b * cNQ + q)) * 768 + h * cD + lane]));
  __syncthreads();
  float lmax = -1e30f;
  for (int k = lane; k < cNQ; k += 64) {
    const short8_t* kr = (const short8_t*)(qkv + ((size_t)(b * cNQ + k)) * 768 + cE + h * cD);
    short8_t c0 = kr[0], c1 = kr[1], c2 = kr[2], c3 = kr[3];
    float s = 0.f;
#pragma unroll
    for (int j = 0; j < 8; ++j) s += qv[j] * bf2f(c0[j]);
#pragma unroll
    for (int j = 0; j < 8; ++j) s += qv[8 + j] * bf2f(c1[j]);
#pragma unroll
    for (int j = 0; j < 8; ++j) s += qv[16 + j] * bf2f(c2[j]);
#pragma unroll
    for (int j = 0; j < 8; ++j) s += qv[24 + j] * bf2f(c3[j]);
    s *= kScale;
    sc[k] = s;
    lmax = fmaxf(lmax, s);
  }
  for (int off = 32; off; off >>= 1) lmax = fmaxf(lmax, __shfl_xor(lmax, off));
  __syncthreads();
  float lsum = 0.f;
  for (int k = lane; k < cNQ; k += 64) {
    float e = __expf(sc[k] - lmax);
    sc[k] = e;
    lsum += e;
  }
  for (int off = 32; off; off >>= 1) lsum += __shfl_xor(lsum, off);
  __syncthreads();
  int d = lane & 31, half = lane >> 5;
  float acc = 0.f;
  for (int k = half * 150; k < half * 150 + 150; ++k)
    acc += sc[k] * bf2f(__builtin_bit_cast(short, qkv[((size_t)(b * cNQ + k)) * 768 + 2 * cE + h * cD + d]));
  acc += __shfl_down(acc, 32);
  if (lane < 32) out[((size_t)(b * cNQ + q)) * cE + h * cD + d] = acc / lsum;
}

// ---------------- flash masked cross-attention ----------------
// Block: (q-tile of 16) x head x batch; 4 waves, wave w owns keys [w*1024,(w+1)*1024).
// No-max softmax (scores are O(1) by construction): p = mask ? exp(s*scale) : 0.
// Row-sums via ones-MFMA. Wave-private LDS -> no barriers in the K loop.
__global__ __launch_bounds__(256) void attn_cross_flash(
    const float* __restrict__ q0, const __hip_bfloat16* __restrict__ k0p,
    const __hip_bfloat16* __restrict__ v0p, const unsigned* __restrict__ mb0,
    float* __restrict__ o0,
    size_t strQ, size_t strKV, size_t strM, size_t strO) {
  int qt = blockIdx.x, h = blockIdx.y, bz = blockIdx.z;
  const float* q = q0 + (size_t)bz * strQ;
  const __hip_bfloat16* K = k0p + (size_t)bz * strKV;
  const __hip_bfloat16* V = v0p + (size_t)bz * strKV;
  const unsigned* mb = mb0 + (size_t)bz * strM;
  float* out = o0 + (size_t)bz * strO;

  int tid = threadIdx.x, lane = tid & 63, wave = tid >> 6;
  int n16 = lane & 15, quad = lane >> 4;
  int qbase = qt * 16;

  __shared__ short sP[4][16][36];
  __shared__ short sV[4][32][36];
  __shared__ float smO[4][16][32];
  __shared__ float smL[4][16];

  // Q A-frag: lane holds Q[qbase+n16][h*32 + quad*8 + j]
  short8_t qfrag = 0;
  {
    int qr = qbase + n16;
    if (qr < cNQ) {
      const float* qp = q + (size_t)qr * cE + h * cD + quad * 8;
#pragma unroll
      for (int j = 0; j < 8; ++j) qfrag[j] = f2bf(qp[j]);
    }
  }
  short8_t ones;
#pragma unroll
  for (int j = 0; j < 8; ++j) ones[j] = f2bf(1.0f);

  float4_t accO0 = {0.f, 0.f, 0.f, 0.f};
  float4_t accO1 = {0.f, 0.f, 0.f, 0.f};
  float4_t accL  = {0.f, 0.f, 0.f, 0.f};
  float4_t zero4 = {0.f, 0.f, 0.f, 0.f};

  for (int step = 0; step < 32; ++step) {
    int koff = wave * 1024 + step * 32;
    // ---- stage V tile (32 keys x 32 dims) into wave-private LDS ----
    {
      int k2 = lane & 31, dq = (lane >> 5) * 16;
      const __hip_bfloat16* vp = V + (size_t)(koff + k2) * cE + h * cD + dq;
      short8_t v0 = *(const short8_t*)vp;
      short8_t v1 = *(const short8_t*)(vp + 8);
      short* dst = &sV[wave][k2][dq];
      *(short4_t*)(dst)     = (short4_t){v0[0], v0[1], v0[2], v0[3]};
      *(short4_t*)(dst + 4) = (short4_t){v0[4], v0[5], v0[6], v0[7]};
      *(short4_t*)(dst + 8) = (short4_t){v1[0], v1[1], v1[2], v1[3]};
      *(short4_t*)(dst + 12)= (short4_t){v1[4], v1[5], v1[6], v1[7]};
    }
    // ---- S = Q.K^T for 2x16 keys ----
    short8_t kf0, kf1;
    {
      const __hip_bfloat16* kp0 = K + (size_t)(koff + n16) * cE + h * cD + quad * 8;
      const __hip_bfloat16* kp1 = K + (size_t)(koff + 16 + n16) * cE + h * cD + quad * 8;
      kf0 = *(const short8_t*)kp0;
      kf1 = *(const short8_t*)kp1;
    }
    float4_t s0 = __builtin_amdgcn_mfma_f32_16x16x32_bf16(qfrag, kf0, zero4, 0, 0, 0);
    float4_t s1 = __builtin_amdgcn_mfma_f32_16x16x32_bf16(qfrag, kf1, zero4, 0, 0, 0);
    // ---- mask + exp, write P (bf16) to LDS ----
    int word = koff >> 5;
#pragma unroll
    for (int r = 0; r < 4; ++r) {
      int qr = qbase + quad * 4 + r;
      unsigned mw = (qr < cNQ) ? mb[(size_t)qr * 128 + word] : 0u;
      float p0 = ((mw >> n16) & 1u)        ? __expf(s0[r] * kScale) : 0.f;
      float p1 = ((mw >> (16 + n16)) & 1u) ? __expf(s1[r] * kScale) : 0.f;
      sP[wave][quad * 4 + r][n16]      = f2bf(p0);
      sP[wave][quad * 4 + r][16 + n16] = f2bf(p1);
    }
    // ---- P A-frag + V B-frags, accumulate O and l ----
    short4_t plo = *(const short4_t*)&sP[wave][n16][quad * 8];
    short4_t phi = *(const short4_t*)&sP[wave][n16][quad * 8 + 4];
    short8_t pfrag = {plo[0], plo[1], plo[2], plo[3], phi[0], phi[1], phi[2], phi[3]};
    short8_t vf0, vf1;
#pragma unroll
    for (int j = 0; j < 8; ++j) {
      vf0[j] = sV[wave][quad * 8 + j][n16];
      vf1[j] = sV[wave][quad * 8 + j][16 + n16];
    }
    accO0 = __builtin_amdgcn_mfma_f32_16x16x32_bf16(pfrag, vf0, accO0, 0, 0, 0);
    accO1 = __builtin_amdgcn_mfma_f32_16x16x32_bf16(pfrag, vf1, accO1, 0, 0, 0);
    accL  = __builtin_amdgcn_mfma_f32_16x16x32_bf16(pfrag, ones, accL, 0, 0, 0);
  }

  // ---- cross-wave merge ----
#pragma unroll
  for (int r = 0; r < 4; ++r) {
    smO[wave][quad * 4 + r][n16]      = accO0[r];
    smO[wave][quad * 4 + r][16 + n16] = accO1[r];
  }
  if (n16 == 0) {
#pragma unroll
    for (int r = 0; r < 4; ++r) smL[wave][quad * 4 + r] = accL[r];
  }
  __syncthreads();
  for (int idx = tid; idx < 512; idx += 256) {
    int row = idx >> 5, col = idx & 31;
    if (qbase + row >= cNQ) continue;
    float o = smO[0][row][col] + smO[1][row][col] + smO[2][row][col] + smO[3][row][col];
    float l = smL[0][row] + smL[1][row] + smL[2][row] + smL[3][row];
    out[(size_t)(qbase + row) * cE + h * cD + col] = o / l;
  }
}

// ---------------- residual + LayerNorm (in-place on t), one wave per row ----------------
__global__ __launch_bounds__(64) void add_ln_k(float* __restrict__ t, const float* __restrict__ delta,
                                               const float* __restrict__ g,
                                               const float* __restrict__ bb) {
  int r = blockIdx.x, lane = threadIdx.x;
  size_t base = (size_t)r * cE + lane * 4;
  float x[4];
  float s = 0.f;
#pragma unroll
  for (int i = 0; i < 4; ++i) { x[i] = t[base + i] + delta[base + i]; s += x[i]; }
  for (int off = 32; off; off >>= 1) s += __shfl_xor(s, off);
  float mean = s * (1.f / cE);
  float v = 0.f;
#pragma unroll
  for (int i = 0; i < 4; ++i) { float dd = x[i] - mean; v += dd * dd; }
  for (int off = 32; off; off >>= 1) v += __shfl_xor(v, off);
  float rstd = rsqrtf(v * (1.f / cE) + 1e-5f);
#pragma unroll
  for (int i = 0; i < 4; ++i)
    t[base + i] = (x[i] - mean) * rstd * g[lane * 4 + i] + bb[lane * 4 + i];
}

// ---------------- final LayerNorm -> fp32 out ----------------
__global__ __launch_bounds__(64) void final_ln_k(const float* __restrict__ t,
                                                 const float* __restrict__ g,
                                                 const float* __restrict__ bb,
                                                 float* __restrict__ out) {
  int r = blockIdx.x, lane = threadIdx.x;
  size_t base = (size_t)r * cE + lane * 4;
  float x[4];
  float s = 0.f;
#pragma unroll
  for (int i = 0; i < 4; ++i) { x[i] = t[base + i]; s += x[i]; }
  for (int off = 32; off; off >>= 1) s += __shfl_xor(s, off);
  float mean = s * (1.f / cE);
  float v = 0.f;
#pragma unroll
  for (int i = 0; i < 4; ++i) { float dd = x[i] - mean; v += dd * dd; }
  for (int off = 32; off; off >>= 1) v += __shfl_xor(v, off);
  float rstd = rsqrtf(v * (1.f / cE) + 1e-5f);
#pragma unroll
  for (int i = 0; i < 4; ++i)
    out[base + i] = (x[i] - mean) * rstd * g[lane * 4 + i] + bb[lane * 4 + i];
}

extern "C" void kernel_launch(void* const* d_in, const int* in_sizes, int n_in,
                              void* d_out, int out_size, void* d_ws, size_t ws_size,
                              hipStream_t stream) {
  (void)in_sizes; (void)n_in; (void)out_size;
  const float* tgt    = (const float*)d_in[0];
  const float* memory = (const float*)d_in[1];
  const int*   gmask  = (const int*)d_in[2];
  const float* sa_wqkv = (const float*)d_in[3];
  const float* sa_bqkv = (const float*)d_in[4];
  const float* sa_wo   = (const float*)d_in[5];
  const float* sa_bo   = (const float*)d_in[6];
  const float* ca_wq   = (const float*)d_in[7];
  const float* ca_bq   = (const float*)d_in[8];
  const float* ca_wk   = (const float*)d_in[9];
  const float* ca_bk   = (const float*)d_in[10];
  const float* ca_wv   = (const float*)d_in[11];
  const float* ca_bv   = (const float*)d_in[12];
  const float* ca_wo   = (const float*)d_in[13];
  const float* ca_bo   = (const float*)d_in[14];
  const float* f_w1    = (const float*)d_in[15];
  const float* f_b1    = (const float*)d_in[16];
  const float* f_w2    = (const float*)d_in[17];
  const float* f_b2    = (const float*)d_in[18];
  const float* ln1g    = (const float*)d_in[19];
  const float* ln1b    = (const float*)d_in[20];
  const float* ln2g    = (const float*)d_in[21];
  const float* ln2b    = (const float*)d_in[22];
  const float* ln3g    = (const float*)d_in[23];
  const float* ln3b    = (const float*)d_in[24];
  const float* lnfg    = (const float*)d_in[25];
  const float* lnfb    = (const float*)d_in[26];

  // workspace layout
  char* wp = (char*)d_ws;
  float* t  = (float*)wp;  wp += (size_t)MT * cE * 4;   // 2.46 MB
  float* s1 = (float*)wp;  wp += (size_t)MT * cE * 4;
  float* s2 = (float*)wp;  wp += (size_t)MT * cE * 4;
  __hip_bfloat16* big = (__hip_bfloat16*)wp; wp += (size_t)MT * cF * 2;  // 9.83 MB (qkv / ffn hidden, bf16)
  unsigned* mbits = (unsigned*)wp; wp += (size_t)MT * 128 * 4;           // 1.23 MB
  __hip_bfloat16* kbuf = (__hip_bfloat16*)wp;
  size_t commonBytes = (size_t)(wp - (char*)d_ws);
  bool fullKV = ws_size >= commonBytes + (size_t)2 * MM * cE * 2;  // +33.6 MB
  size_t kvElems = fullKV ? (size_t)MM * cE : (size_t)cNK * cE;
  __hip_bfloat16* vbuf = kbuf + kvElems;

  copy_f32<<<(MT * cE + 255) / 256, 256, 0, stream>>>(tgt, t, MT * cE);
  pack_mask<<<(MT * cNK) / 256, 256, 0, stream>>>(gmask, mbits, MT * cNK);

  for (int l = 0; l < cL; ++l) {
    const float* wqkv = sa_wqkv + (size_t)l * 3 * cE * cE;
    const float* bqkv = sa_bqkv + (size_t)l * 3 * cE;
    const float* wo   = sa_wo   + (size_t)l * cE * cE;
    const float* bo   = sa_bo   + (size_t)l * cE;
    const float* wq   = ca_wq   + (size_t)l * cE * cE;
    const float* bq   = ca_bq   + (size_t)l * cE;
    const float* wk   = ca_wk   + (size_t)l * cE * cE;
    const float* bk   = ca_bk   + (size_t)l * cE;
    const float* wv   = ca_wv   + (size_t)l * cE * cE;
    const float* bv   = ca_bv   + (size_t)l * cE;
    const float* wco  = ca_wo   + (size_t)l * cE * cE;
    const float* bco  = ca_bo   + (size_t)l * cE;
    const float* w1   = f_w1    + (size_t)l * cF * cE;
    const float* b1   = f_b1    + (size_t)l * cF;
    const float* w2   = f_w2    + (size_t)l * cE * cF;
    const float* b2   = f_b2    + (size_t)l * cE;

    // 1) qkv = t @ wqkv^T + bqkv (2400x768, bf16) -> big
    gemm_mfma<float, 0, __hip_bfloat16><<<dim3(38, 12), 256, 0, stream>>>(t, wqkv, bqkv, big, MT, 3 * cE, cE);
    // 2) self attention -> s1 (fp32)
    attn_self_k<<<dim3(cNQ, cH, cB), 64, 0, stream>>>(big, s1);
    // 3) sa out proj -> s2
    gemm_mfma<float, 0, float><<<dim3(38, 4), 256, 0, stream>>>(s1, wo, bo, s2, MT, cE, cE);
    // 4) t = LN(t + s2)
    add_ln_k<<<MT, 64, 0, stream>>>(t, s2, ln1g + (size_t)l * cE, ln1b + (size_t)l * cE);
    // 5) q = t @ wq^T + bq -> s1
    gemm_mfma<float, 0, float><<<dim3(38, 4), 256, 0, stream>>>(t, wq, bq, s1, MT, cE, cE);
    // 6-8) K/V projection (bf16) + flash cross attention -> s2
    if (fullKV) {
      gemm_mfma<float, 0, __hip_bfloat16><<<dim3(512, 4), 256, 0, stream>>>(memory, wk, bk, kbuf, MM, cE, cE);
      gemm_mfma<float, 0, __hip_bfloat16><<<dim3(512, 4), 256, 0, stream>>>(memory, wv, bv, vbuf, MM, cE, cE);
      attn_cross_flash<<<dim3(19, cH, cB), 256, 0, stream>>>(
          s1, kbuf, vbuf, mbits, s2,
          (size_t)cNQ * cE, (size_t)cNK * cE, (size_t)cNQ * 128, (size_t)cNQ * cE);
    } else {
      for (int b = 0; b < cB; ++b) {
        const float* memb = memory + (size_t)b * cNK * cE;
        gemm_mfma<float, 0, __hip_bfloat16><<<dim3(64, 4), 256, 0, stream>>>(memb, wk, bk, kbuf, cNK, cE, cE);
        gemm_mfma<float, 0, __hip_bfloat16><<<dim3(64, 4), 256, 0, stream>>>(memb, wv, bv, vbuf, cNK, cE, cE);
        attn_cross_flash<<<dim3(19, cH, 1), 256, 0, stream>>>(
            s1 + (size_t)b * cNQ * cE, kbuf, vbuf, mbits + (size_t)b * cNQ * 128,
            s2 + (size_t)b * cNQ * cE, 0, 0, 0, 0);
      }
    }
    // 9) ca out proj -> s1
    gemm_mfma<float, 0, float><<<dim3(38, 4), 256, 0, stream>>>(s2, wco, bco, s1, MT, cE, cE);
    // 10) t = LN(t + s1)
    add_ln_k<<<MT, 64, 0, stream>>>(t, s1, ln2g + (size_t)l * cE, ln2b + (size_t)l * cE);
    // 11) hidden = relu(t @ w1^T + b1) (bf16) -> big
    gemm_mfma<float, 1, __hip_bfloat16><<<dim3(38, 32), 256, 0, stream>>>(t, w1, b1, big, MT, cF, cE);
    // 12) f = hidden @ w2^T + b2 -> s1
    gemm_mfma<__hip_bfloat16, 0, float><<<dim3(38, 4), 256, 0, stream>>>(big, w2, b2, s1, MT, cE, cF);
    // 13) t = LN(t + s1)
    add_ln_k<<<MT, 64, 0, stream>>>(t, s1, ln3g + (size_t)l * cE, ln3b + (size_t)l * cE);
  }

  final_ln_k<<<MT, 64, 0, stream>>>(t, lnfg, lnfb, (float*)d_out);
}

// Round 7
// 1831.739 us; speedup vs baseline: 7.5927x; 1.6416x over previous
//
#include <hip/hip_runtime.h>
#include <hip/hip_bf16.h>

// Problem dims
constexpr int cB = 8, cNQ = 300, cNK = 4096, cE = 256, cH = 8, cD = 32, cF = 2048, cL = 6;
constexpr int MT = cB * cNQ;    // 2400 rows of target stream
constexpr int MM = cB * cNK;    // 32768 rows of memory stream
constexpr float kScale = 0.17677669529663687f;  // 32^-0.5

typedef __attribute__((ext_vector_type(8))) short short8_t;   // 8 bf16 in 4 VGPRs
typedef __attribute__((ext_vector_type(4))) short short4_t;   // 8B
typedef __attribute__((ext_vector_type(4))) float float4_t;

__device__ inline short f2bf(float x) {
  __hip_bfloat16 h = __float2bfloat16(x);
  return __builtin_bit_cast(short, h);
}
__device__ inline float bf2f(short s) {
  return (float)__builtin_bit_cast(__hip_bfloat16, s);
}

// ---------------- copy fp32 ----------------
__global__ void copy_f32(const float* __restrict__ in, float* __restrict__ out, int n) {
  int i = blockIdx.x * 256 + threadIdx.x;
  if (i < n) out[i] = in[i];
}
// ---------------- cast fp32 -> bf16 ----------------
__global__ void cast_f32_bf16(const float* __restrict__ in, __hip_bfloat16* __restrict__ out, int n) {
  int i = blockIdx.x * 256 + threadIdx.x;
  if (i < n) out[i] = __float2bfloat16(in[i]);
}

// ---------------- pack geometry mask into bits (one-time) ----------------
__global__ void pack_mask(const int* __restrict__ m, unsigned* __restrict__ bits, int n) {
  int i = blockIdx.x * 256 + threadIdx.x;
  bool on = (i < n) && (m[i] != 0);
  unsigned long long bal = __ballot(on);
  int lane = threadIdx.x & 63;
  int base = (blockIdx.x * 256 + (threadIdx.x & ~63)) >> 5;  // word idx of lane 0
  if (lane == 0)  bits[base]     = (unsigned)bal;
  if (lane == 32) bits[base + 1] = (unsigned)(bal >> 32);
}

// ---------------- MFMA GEMM: C[M,N] = A[M,K] . W[N,K]^T + bias[N] ----------------
// TA: float (cast in staging) or __hip_bfloat16 (direct). W fp32. fp32 accumulate.
// EPI: 0=none, 1=relu. TOUT: float or __hip_bfloat16.
// HEADMAJOR: write C as [n>>5][M][32] (requires N==256, TOUT=bf16) for attention K/V.
template<typename TA, int EPI, typename TOUT, bool HEADMAJOR>
__global__ __launch_bounds__(256) void gemm_mfma(const TA* __restrict__ A,
                                                 const float* __restrict__ W,
                                                 const float* __restrict__ bias,
                                                 TOUT* __restrict__ C,
                                                 int M, int N, int K) {
  constexpr int LDSS = 72;  // 64 + 8 bf16 pad
  __shared__ short As[64][LDSS];
  __shared__ short Ws[64][LDSS];
  int tid = threadIdx.x;
  int bm = blockIdx.x * 64, bn = blockIdx.y * 64;
  int lane = tid & 63, wave = tid >> 6;
  int m16 = lane & 15, quad = lane >> 4;
  int wm = (wave >> 1) * 32, wn = (wave & 1) * 32;

  int srow = tid >> 2;
  int kc = (tid & 3) * 16;
  bool aok = (bm + srow) < M;

  float4_t acc[2][2];
#pragma unroll
  for (int i = 0; i < 2; ++i)
#pragma unroll
    for (int j = 0; j < 2; ++j) acc[i][j] = (float4_t){0.f, 0.f, 0.f, 0.f};

  for (int k0 = 0; k0 < K; k0 += 64) {
    if constexpr (__hip_internal::is_same<TA, float>::value) {
      const float* src = A + (size_t)(bm + srow) * K + k0 + kc;
      short8_t p0, p1;
#pragma unroll
      for (int u = 0; u < 8; ++u) p0[u] = aok ? f2bf(src[u]) : (short)0;
#pragma unroll
      for (int u = 0; u < 8; ++u) p1[u] = aok ? f2bf(src[8 + u]) : (short)0;
      *(short8_t*)&As[srow][kc] = p0;
      *(short8_t*)&As[srow][kc + 8] = p1;
    } else {
      const TA* src = A + (size_t)(bm + srow) * K + k0 + kc;
      short8_t z = 0;
      short8_t p0 = aok ? *(const short8_t*)src : z;
      short8_t p1 = aok ? *(const short8_t*)(src + 8) : z;
      *(short8_t*)&As[srow][kc] = p0;
      *(short8_t*)&As[srow][kc + 8] = p1;
    }
    {
      const float* src = W + (size_t)(bn + srow) * K + k0 + kc;
      short8_t p0, p1;
#pragma unroll
      for (int u = 0; u < 8; ++u) p0[u] = f2bf(src[u]);
#pragma unroll
      for (int u = 0; u < 8; ++u) p1[u] = f2bf(src[8 + u]);
      *(short8_t*)&Ws[srow][kc] = p0;
      *(short8_t*)&Ws[srow][kc + 8] = p1;
    }
    __syncthreads();
#pragma unroll
    for (int kk = 0; kk < 2; ++kk) {
      short8_t aF[2], bF[2];
#pragma unroll
      for (int i = 0; i < 2; ++i)
        aF[i] = *(const short8_t*)&As[wm + i * 16 + m16][kk * 32 + quad * 8];
#pragma unroll
      for (int j = 0; j < 2; ++j)
        bF[j] = *(const short8_t*)&Ws[wn + j * 16 + m16][kk * 32 + quad * 8];
#pragma unroll
      for (int i = 0; i < 2; ++i)
#pragma unroll
        for (int j = 0; j < 2; ++j)
          acc[i][j] = __builtin_amdgcn_mfma_f32_16x16x32_bf16(aF[i], bF[j], acc[i][j], 0, 0, 0);
    }
    __syncthreads();
  }

  // epilogue: C/D layout col=lane&15, row=quad*4+reg
#pragma unroll
  for (int i = 0; i < 2; ++i) {
#pragma unroll
    for (int r = 0; r < 4; ++r) {
      int m = bm + wm + i * 16 + quad * 4 + r;
      if (m >= M) continue;
#pragma unroll
      for (int j = 0; j < 2; ++j) {
        int n = bn + wn + j * 16 + m16;
        float v = acc[i][j][r] + bias[n];
        if (EPI == 1) v = fmaxf(v, 0.f);
        if constexpr (HEADMAJOR) {
          C[((size_t)(n >> 5) * M + m) * 32 + (n & 31)] = __float2bfloat16(v);
        } else if constexpr (__hip_internal::is_same<TOUT, float>::value) {
          C[(size_t)m * N + n] = v;
        } else {
          C[(size_t)m * N + n] = __float2bfloat16(v);
        }
      }
    }
  }
}

// ---------------- unified flash attention (self & masked cross) ----------------
// Grid: (H*B, q-tiles of 32). blockIdx.x = h + 8*bz  -> all q-tiles of one (h,b)
// land on the same XCD (stride 64 in dispatch order).
// 4 waves; wave w owns keys [w*keysPerWave, (w+1)*keysPerWave), 32 keys/step.
// No-max softmax: p = pred ? exp(s*scale) : 0 (scores O(1) by construction).
// Wave-private LDS -> barrier-free K loop. Row-sums via ones-MFMA.
template<typename TQ, bool MASKED>
__global__ __launch_bounds__(256) void attn_flash(
    const TQ* __restrict__ qb, size_t strQb, size_t strQh, int qRowStr,
    const __hip_bfloat16* __restrict__ kb, const __hip_bfloat16* __restrict__ vb,
    size_t strKb, size_t strKh, int kRowStr,
    const unsigned* __restrict__ mb0, size_t strMb, int mWords,
    float* __restrict__ ob, size_t strOb,
    int nq, int nk, int keysPerWave) {
  int hb = blockIdx.x;
  int h = hb & 7, bz = hb >> 3;
  int qt = blockIdx.y;
  const TQ* q = qb + (size_t)bz * strQb + (size_t)h * strQh;
  const __hip_bfloat16* K = kb + (size_t)bz * strKb + (size_t)h * strKh;
  const __hip_bfloat16* V = vb + (size_t)bz * strKb + (size_t)h * strKh;
  const unsigned* mb = MASKED ? (mb0 + (size_t)bz * strMb) : nullptr;
  float* out = ob + (size_t)bz * strOb + h * cD;

  int tid = threadIdx.x, lane = tid & 63, wave = tid >> 6;
  int n16 = lane & 15, quad = lane >> 4;
  int qbase = qt * 32;

  __shared__ short sP[4][32][36];
  __shared__ short sV[4][32][36];
  __shared__ float smO[4][32][32];
  __shared__ float smL[4][32];

  // Q A-frags: qf[qi] holds Q[qbase+qi*16+n16][quad*8+j]
  short8_t qf[2];
#pragma unroll
  for (int qi = 0; qi < 2; ++qi) {
    qf[qi] = 0;
    int qr = qbase + qi * 16 + n16;
    if (qr < nq) {
      const TQ* qp = q + (size_t)qr * qRowStr + quad * 8;
      if constexpr (__hip_internal::is_same<TQ, float>::value) {
#pragma unroll
        for (int j = 0; j < 8; ++j) qf[qi][j] = f2bf(qp[j]);
      } else {
        qf[qi] = *(const short8_t*)qp;
      }
    }
  }
  short8_t ones;
#pragma unroll
  for (int j = 0; j < 8; ++j) ones[j] = f2bf(1.0f);

  float4_t accO[2][2], accL[2];
#pragma unroll
  for (int qi = 0; qi < 2; ++qi) {
    accL[qi] = (float4_t){0.f, 0.f, 0.f, 0.f};
#pragma unroll
    for (int di = 0; di < 2; ++di) accO[qi][di] = (float4_t){0.f, 0.f, 0.f, 0.f};
  }
  float4_t zero4 = {0.f, 0.f, 0.f, 0.f};

  int steps = keysPerWave >> 5;
  for (int st = 0; st < steps; ++st) {
    int koff = wave * keysPerWave + st * 32;
    // ---- stage V tile (32 keys x 32 dims), wave-private ----
    {
      int k2 = lane & 31, dq = (lane >> 5) * 16;
      const __hip_bfloat16* vp = V + (size_t)(koff + k2) * kRowStr + dq;
      short8_t v0 = *(const short8_t*)vp;
      short8_t v1 = *(const short8_t*)(vp + 8);
      short* dst = &sV[wave][k2][dq];
      *(short4_t*)(dst)      = (short4_t){v0[0], v0[1], v0[2], v0[3]};
      *(short4_t*)(dst + 4)  = (short4_t){v0[4], v0[5], v0[6], v0[7]};
      *(short4_t*)(dst + 8)  = (short4_t){v1[0], v1[1], v1[2], v1[3]};
      *(short4_t*)(dst + 12) = (short4_t){v1[4], v1[5], v1[6], v1[7]};
    }
    // ---- K B-frags for 2x16 keys ----
    short8_t kf0 = *(const short8_t*)(K + (size_t)(koff + n16) * kRowStr + quad * 8);
    short8_t kf1 = *(const short8_t*)(K + (size_t)(koff + 16 + n16) * kRowStr + quad * 8);
    // ---- S = Q.K^T ----
    float4_t s00 = __builtin_amdgcn_mfma_f32_16x16x32_bf16(qf[0], kf0, zero4, 0, 0, 0);
    float4_t s01 = __builtin_amdgcn_mfma_f32_16x16x32_bf16(qf[0], kf1, zero4, 0, 0, 0);
    float4_t s10 = __builtin_amdgcn_mfma_f32_16x16x32_bf16(qf[1], kf0, zero4, 0, 0, 0);
    float4_t s11 = __builtin_amdgcn_mfma_f32_16x16x32_bf16(qf[1], kf1, zero4, 0, 0, 0);
    // ---- mask + exp -> P (bf16) in LDS ----
    int word = koff >> 5;
    bool v0ok = (koff + n16) < nk;
    bool v1ok = (koff + 16 + n16) < nk;
#pragma unroll
    for (int qi = 0; qi < 2; ++qi) {
      const float4_t& sa = qi ? s10 : s00;
      const float4_t& sb = qi ? s11 : s01;
#pragma unroll
      for (int r = 0; r < 4; ++r) {
        int qr = qbase + qi * 16 + quad * 4 + r;
        bool p0ok = v0ok, p1ok = v1ok;
        if (MASKED) {
          unsigned mw = (qr < nq) ? mb[(size_t)qr * mWords + word] : 0u;
          p0ok = p0ok && ((mw >> n16) & 1u);
          p1ok = p1ok && ((mw >> (16 + n16)) & 1u);
        }
        float p0 = p0ok ? __expf(sa[r] * kScale) : 0.f;
        float p1 = p1ok ? __expf(sb[r] * kScale) : 0.f;
        sP[wave][qi * 16 + quad * 4 + r][n16]      = f2bf(p0);
        sP[wave][qi * 16 + quad * 4 + r][16 + n16] = f2bf(p1);
      }
    }
    // ---- P A-frags + V B-frags, accumulate ----
    short8_t vf0, vf1;
#pragma unroll
    for (int j = 0; j < 8; ++j) {
      vf0[j] = sV[wave][quad * 8 + j][n16];
      vf1[j] = sV[wave][quad * 8 + j][16 + n16];
    }
#pragma unroll
    for (int qi = 0; qi < 2; ++qi) {
      short4_t plo = *(const short4_t*)&sP[wave][qi * 16 + n16][quad * 8];
      short4_t phi = *(const short4_t*)&sP[wave][qi * 16 + n16][quad * 8 + 4];
      short8_t pfrag = {plo[0], plo[1], plo[2], plo[3], phi[0], phi[1], phi[2], phi[3]};
      accO[qi][0] = __builtin_amdgcn_mfma_f32_16x16x32_bf16(pfrag, vf0, accO[qi][0], 0, 0, 0);
      accO[qi][1] = __builtin_amdgcn_mfma_f32_16x16x32_bf16(pfrag, vf1, accO[qi][1], 0, 0, 0);
      accL[qi]    = __builtin_amdgcn_mfma_f32_16x16x32_bf16(pfrag, ones, accL[qi], 0, 0, 0);
    }
  }

  // ---- cross-wave merge ----
#pragma unroll
  for (int qi = 0; qi < 2; ++qi) {
#pragma unroll
    for (int r = 0; r < 4; ++r) {
      smO[wave][qi * 16 + quad * 4 + r][n16]      = accO[qi][0][r];
      smO[wave][qi * 16 + quad * 4 + r][16 + n16] = accO[qi][1][r];
    }
    if (n16 == 0) {
#pragma unroll
      for (int r = 0; r < 4; ++r) smL[wave][qi * 16 + quad * 4 + r] = accL[qi][r];
    }
  }
  __syncthreads();
  for (int idx = tid; idx < 1024; idx += 256) {
    int row = idx >> 5, col = idx & 31;
    if (qbase + row >= nq) continue;
    float o = smO[0][row][col] + smO[1][row][col] + smO[2][row][col] + smO[3][row][col];
    float l = smL[0][row] + smL[1][row] + smL[2][row] + smL[3][row];
    out[(size_t)(qbase + row) * cE + col] = o / l;
  }
}

// ---------------- residual + LayerNorm (in-place on t), one wave per row ----------------
__global__ __launch_bounds__(64) void add_ln_k(float* __restrict__ t, const float* __restrict__ delta,
                                               const float* __restrict__ g,
                                               const float* __restrict__ bb) {
  int r = blockIdx.x, lane = threadIdx.x;
  size_t base = (size_t)r * cE + lane * 4;
  float x[4];
  float s = 0.f;
#pragma unroll
  for (int i = 0; i < 4; ++i) { x[i] = t[base + i] + delta[base + i]; s += x[i]; }
  for (int off = 32; off; off >>= 1) s += __shfl_xor(s, off);
  float mean = s * (1.f / cE);
  float v = 0.f;
#pragma unroll
  for (int i = 0; i < 4; ++i) { float dd = x[i] - mean; v += dd * dd; }
  for (int off = 32; off; off >>= 1) v += __shfl_xor(v, off);
  float rstd = rsqrtf(v * (1.f / cE) + 1e-5f);
#pragma unroll
  for (int i = 0; i < 4; ++i)
    t[base + i] = (x[i] - mean) * rstd * g[lane * 4 + i] + bb[lane * 4 + i];
}

// ---------------- final LayerNorm -> fp32 out ----------------
__global__ __launch_bounds__(64) void final_ln_k(const float* __restrict__ t,
                                                 const float* __restrict__ g,
                                                 const float* __restrict__ bb,
                                                 float* __restrict__ out) {
  int r = blockIdx.x, lane = threadIdx.x;
  size_t base = (size_t)r * cE + lane * 4;
  float x[4];
  float s = 0.f;
#pragma unroll
  for (int i = 0; i < 4; ++i) { x[i] = t[base + i]; s += x[i]; }
  for (int off = 32; off; off >>= 1) s += __shfl_xor(s, off);
  float mean = s * (1.f / cE);
  float v = 0.f;
#pragma unroll
  for (int i = 0; i < 4; ++i) { float dd = x[i] - mean; v += dd * dd; }
  for (int off = 32; off; off >>= 1) v += __shfl_xor(v, off);
  float rstd = rsqrtf(v * (1.f / cE) + 1e-5f);
#pragma unroll
  for (int i = 0; i < 4; ++i)
    out[base + i] = (x[i] - mean) * rstd * g[lane * 4 + i] + bb[lane * 4 + i];
}

extern "C" void kernel_launch(void* const* d_in, const int* in_sizes, int n_in,
                              void* d_out, int out_size, void* d_ws, size_t ws_size,
                              hipStream_t stream) {
  (void)in_sizes; (void)n_in; (void)out_size;
  const float* tgt    = (const float*)d_in[0];
  const float* memory = (const float*)d_in[1];
  const int*   gmask  = (const int*)d_in[2];
  const float* sa_wqkv = (const float*)d_in[3];
  const float* sa_bqkv = (const float*)d_in[4];
  const float* sa_wo   = (const float*)d_in[5];
  const float* sa_bo   = (const float*)d_in[6];
  const float* ca_wq   = (const float*)d_in[7];
  const float* ca_bq   = (const float*)d_in[8];
  const float* ca_wk   = (const float*)d_in[9];
  const float* ca_bk   = (const float*)d_in[10];
  const float* ca_wv   = (const float*)d_in[11];
  const float* ca_bv   = (const float*)d_in[12];
  const float* ca_wo   = (const float*)d_in[13];
  const float* ca_bo   = (const float*)d_in[14];
  const float* f_w1    = (const float*)d_in[15];
  const float* f_b1    = (const float*)d_in[16];
  const float* f_w2    = (const float*)d_in[17];
  const float* f_b2    = (const float*)d_in[18];
  const float* ln1g    = (const float*)d_in[19];
  const float* ln1b    = (const float*)d_in[20];
  const float* ln2g    = (const float*)d_in[21];
  const float* ln2b    = (const float*)d_in[22];
  const float* ln3g    = (const float*)d_in[23];
  const float* ln3b    = (const float*)d_in[24];
  const float* lnfg    = (const float*)d_in[25];
  const float* lnfb    = (const float*)d_in[26];

  // workspace layout
  char* wp = (char*)d_ws;
  float* t  = (float*)wp;  wp += (size_t)MT * cE * 4;
  float* s1 = (float*)wp;  wp += (size_t)MT * cE * 4;
  float* s2 = (float*)wp;  wp += (size_t)MT * cE * 4;
  __hip_bfloat16* big = (__hip_bfloat16*)wp; wp += (size_t)MT * cF * 2;  // qkv / ffn hidden
  unsigned* mbits = (unsigned*)wp; wp += (size_t)MT * 128 * 4;
  __hip_bfloat16* kbuf = (__hip_bfloat16*)wp;
  size_t commonBytes = (size_t)(wp - (char*)d_ws);
  size_t kvBytes = (size_t)MM * cE * 2;       // one full-batch K or V, bf16
  size_t memBytes = (size_t)MM * cE * 2;      // bf16 memory precast
  bool fullKV = ws_size >= commonBytes + 2 * kvBytes;
  bool precast = fullKV && (ws_size >= commonBytes + 2 * kvBytes + memBytes);
  size_t kvElems = fullKV ? (size_t)MM * cE : (size_t)cNK * cE;
  __hip_bfloat16* vbuf = kbuf + kvElems;
  __hip_bfloat16* membf = vbuf + kvElems;  // only valid when precast

  copy_f32<<<(MT * cE + 255) / 256, 256, 0, stream>>>(tgt, t, MT * cE);
  pack_mask<<<(MT * cNK) / 256, 256, 0, stream>>>(gmask, mbits, MT * cNK);
  if (precast)
    cast_f32_bf16<<<(MM * cE + 255) / 256, 256, 0, stream>>>(memory, membf, MM * cE);

  for (int l = 0; l < cL; ++l) {
    const float* wqkv = sa_wqkv + (size_t)l * 3 * cE * cE;
    const float* bqkv = sa_bqkv + (size_t)l * 3 * cE;
    const float* wo   = sa_wo   + (size_t)l * cE * cE;
    const float* bo   = sa_bo   + (size_t)l * cE;
    const float* wq   = ca_wq   + (size_t)l * cE * cE;
    const float* bq   = ca_bq   + (size_t)l * cE;
    const float* wk   = ca_wk   + (size_t)l * cE * cE;
    const float* bk   = ca_bk   + (size_t)l * cE;
    const float* wv   = ca_wv   + (size_t)l * cE * cE;
    const float* bv   = ca_bv   + (size_t)l * cE;
    const float* wco  = ca_wo   + (size_t)l * cE * cE;
    const float* bco  = ca_bo   + (size_t)l * cE;
    const float* w1   = f_w1    + (size_t)l * cF * cE;
    const float* b1   = f_b1    + (size_t)l * cF;
    const float* w2   = f_w2    + (size_t)l * cE * cF;
    const float* b2   = f_b2    + (size_t)l * cE;

    // 1) qkv = t @ wqkv^T + bqkv (2400x768, bf16) -> big
    gemm_mfma<float, 0, __hip_bfloat16, false><<<dim3(38, 12), 256, 0, stream>>>(t, wqkv, bqkv, big, MT, 3 * cE, cE);
    // 2) self attention (flash, unmasked) -> s1 (fp32)
    attn_flash<__hip_bfloat16, false><<<dim3(64, 10), 256, 0, stream>>>(
        big, (size_t)cNQ * 768, 32, 768,
        big + 256, big + 512, (size_t)cNQ * 768, 32, 768,
        nullptr, 0, 0,
        s1, (size_t)cNQ * cE, cNQ, cNQ, 96);
    // 3) sa out proj -> s2
    gemm_mfma<float, 0, float, false><<<dim3(38, 4), 256, 0, stream>>>(s1, wo, bo, s2, MT, cE, cE);
    // 4) t = LN(t + s2)
    add_ln_k<<<MT, 64, 0, stream>>>(t, s2, ln1g + (size_t)l * cE, ln1b + (size_t)l * cE);
    // 5) q = t @ wq^T + bq -> s1
    gemm_mfma<float, 0, float, false><<<dim3(38, 4), 256, 0, stream>>>(t, wq, bq, s1, MT, cE, cE);
    // 6-8) K/V projection (bf16, head-major) + flash cross attention -> s2
    if (fullKV) {
      if (precast) {
        gemm_mfma<__hip_bfloat16, 0, __hip_bfloat16, true><<<dim3(512, 4), 256, 0, stream>>>(membf, wk, bk, kbuf, MM, cE, cE);
        gemm_mfma<__hip_bfloat16, 0, __hip_bfloat16, true><<<dim3(512, 4), 256, 0, stream>>>(membf, wv, bv, vbuf, MM, cE, cE);
      } else {
        gemm_mfma<float, 0, __hip_bfloat16, true><<<dim3(512, 4), 256, 0, stream>>>(memory, wk, bk, kbuf, MM, cE, cE);
        gemm_mfma<float, 0, __hip_bfloat16, true><<<dim3(512, 4), 256, 0, stream>>>(memory, wv, bv, vbuf, MM, cE, cE);
      }
      attn_flash<float, true><<<dim3(64, 10), 256, 0, stream>>>(
          s1, (size_t)cNQ * cE, 32, cE,
          kbuf, vbuf, (size_t)cNK * 32, (size_t)MM * 32, 32,
          mbits, (size_t)cNQ * 128, 128,
          s2, (size_t)cNQ * cE, cNQ, cNK, 1024);
    } else {
      for (int b = 0; b < cB; ++b) {
        const float* memb = memory + (size_t)b * cNK * cE;
        gemm_mfma<float, 0, __hip_bfloat16, true><<<dim3(64, 4), 256, 0, stream>>>(memb, wk, bk, kbuf, cNK, cE, cE);
        gemm_mfma<float, 0, __hip_bfloat16, true><<<dim3(64, 4), 256, 0, stream>>>(memb, wv, bv, vbuf, cNK, cE, cE);
        attn_flash<float, true><<<dim3(8, 10), 256, 0, stream>>>(
            s1 + (size_t)b * cNQ * cE, 0, 32, cE,
            kbuf, vbuf, 0, (size_t)cNK * 32, 32,
            mbits + (size_t)b * cNQ * 128, 0, 128,
            s2 + (size_t)b * cNQ * cE, 0, cNQ, cNK, 1024);
      }
    }
    // 9) ca out proj -> s1
    gemm_mfma<float, 0, float, false><<<dim3(38, 4), 256, 0, stream>>>(s2, wco, bco, s1, MT, cE, cE);
    // 10) t = LN(t + s1)
    add_ln_k<<<MT, 64, 0, stream>>>(t, s1, ln2g + (size_t)l * cE, ln2b + (size_t)l * cE);
    // 11) hidden = relu(t @ w1^T + b1) (bf16) -> big
    gemm_mfma<float, 1, __hip_bfloat16, false><<<dim3(38, 32), 256, 0, stream>>>(t, w1, b1, big, MT, cF, cE);
    // 12) f = hidden @ w2^T + b2 -> s1
    gemm_mfma<__hip_bfloat16, 0, float, false><<<dim3(38, 4), 256, 0, stream>>>(big, w2, b2, s1, MT, cE, cF);
    // 13) t = LN(t + s1)
    add_ln_k<<<MT, 64, 0, stream>>>(t, s1, ln3g + (size_t)l * cE, ln3b + (size_t)l * cE);
  }

  final_ln_k<<<MT, 64, 0, stream>>>(t, lnfg, lnfb, (float*)d_out);
}

// Round 8
// 1633.100 us; speedup vs baseline: 8.5163x; 1.1216x over previous
//
#include <hip/hip_runtime.h>
#include <hip/hip_bf16.h>

// Problem dims
constexpr int cB = 8, cNQ = 300, cNK = 4096, cE = 256, cH = 8, cD = 32, cF = 2048, cL = 6;
constexpr int MT = cB * cNQ;    // 2400 rows of target stream
constexpr int MM = cB * cNK;    // 32768 rows of memory stream
constexpr int cQT = 10;         // q-tiles of 32 (300 -> 10)
constexpr int cKS = 4;          // k-split
constexpr float kScale = 0.17677669529663687f;  // 32^-0.5

typedef __attribute__((ext_vector_type(8))) short short8_t;
typedef __attribute__((ext_vector_type(4))) short short4_t;
typedef __attribute__((ext_vector_type(4))) float float4_t;

__device__ inline short f2bf(float x) {
  __hip_bfloat16 h = __float2bfloat16(x);
  return __builtin_bit_cast(short, h);
}

// ---------------- copy / cast ----------------
__global__ void copy_f32(const float* __restrict__ in, float* __restrict__ out, int n) {
  int i = blockIdx.x * 256 + threadIdx.x;
  if (i < n) out[i] = in[i];
}
__global__ void cast_f32_bf16(const float* __restrict__ in, __hip_bfloat16* __restrict__ out, int n) {
  int i = blockIdx.x * 256 + threadIdx.x;
  if (i < n) out[i] = __float2bfloat16(in[i]);
}

// ---------------- transposed mask pack: mT[b][qt][key], bit j = mask[b][qt*32+j][key] ----
__global__ void pack_mask_T(const int* __restrict__ m, unsigned* __restrict__ mT) {
  int key = blockIdx.x * 256 + threadIdx.x;
  int qt = blockIdx.y, b = blockIdx.z;
  unsigned w = 0;
  for (int j = 0; j < 32; ++j) {
    int q = qt * 32 + j;
    unsigned bit = (q < cNQ) ? (unsigned)(m[((size_t)b * cNQ + q) * cNK + key] != 0) : 0u;
    w |= bit << j;
  }
  mT[((size_t)b * cQT + qt) * cNK + key] = w;
}

// ---------------- MFMA GEMM: C[M,N] = A[M,K] . W[N,K]^T + bias[N] ----------------
// TA: float (cast in staging) or bf16 (direct). W bf16 (precast). fp32 accumulate.
// EPI: 0=none, 1=relu.
// OMODE 0: row-major, stride N, TOUT.  1: K head-major [n>>5][M][32] bf16.
//       2: V transposed [n>>5][n&31][M] bf16 (LDS-transposed coalesced store).
template<typename TA, int EPI, int OMODE, typename TOUT>
__global__ __launch_bounds__(256) void gemm_mfma(const TA* __restrict__ A,
                                                 const __hip_bfloat16* __restrict__ W,
                                                 const float* __restrict__ bias,
                                                 TOUT* __restrict__ C,
                                                 int M, int N, int K) {
  constexpr int LDSS = 72;  // 64 + 8 bf16 pad (144 B rows, 16B aligned)
  __shared__ short As[64][LDSS];
  __shared__ short Ws[64][LDSS];
  int tid = threadIdx.x;
  int bm = blockIdx.x * 64, bn = blockIdx.y * 64;
  int lane = tid & 63, wave = tid >> 6;
  int m16 = lane & 15, quad = lane >> 4;
  int wm = (wave >> 1) * 32, wn = (wave & 1) * 32;

  int srow = tid >> 2;
  int kc = (tid & 3) * 16;
  bool aok = (bm + srow) < M;

  float4_t acc[2][2];
#pragma unroll
  for (int i = 0; i < 2; ++i)
#pragma unroll
    for (int j = 0; j < 2; ++j) acc[i][j] = (float4_t){0.f, 0.f, 0.f, 0.f};

  for (int k0 = 0; k0 < K; k0 += 64) {
    if constexpr (__hip_internal::is_same<TA, float>::value) {
      const float* src = A + (size_t)(bm + srow) * K + k0 + kc;
      short8_t p0, p1;
#pragma unroll
      for (int u = 0; u < 8; ++u) p0[u] = aok ? f2bf(src[u]) : (short)0;
#pragma unroll
      for (int u = 0; u < 8; ++u) p1[u] = aok ? f2bf(src[8 + u]) : (short)0;
      *(short8_t*)&As[srow][kc] = p0;
      *(short8_t*)&As[srow][kc + 8] = p1;
    } else {
      const TA* src = A + (size_t)(bm + srow) * K + k0 + kc;
      short8_t z = 0;
      short8_t p0 = aok ? *(const short8_t*)src : z;
      short8_t p1 = aok ? *(const short8_t*)(src + 8) : z;
      *(short8_t*)&As[srow][kc] = p0;
      *(short8_t*)&As[srow][kc + 8] = p1;
    }
    {
      const __hip_bfloat16* src = W + (size_t)(bn + srow) * K + k0 + kc;
      short8_t p0 = *(const short8_t*)src;
      short8_t p1 = *(const short8_t*)(src + 8);
      *(short8_t*)&Ws[srow][kc] = p0;
      *(short8_t*)&Ws[srow][kc + 8] = p1;
    }
    __syncthreads();
#pragma unroll
    for (int kk = 0; kk < 2; ++kk) {
      short8_t aF[2], bF[2];
#pragma unroll
      for (int i = 0; i < 2; ++i)
        aF[i] = *(const short8_t*)&As[wm + i * 16 + m16][kk * 32 + quad * 8];
#pragma unroll
      for (int j = 0; j < 2; ++j)
        bF[j] = *(const short8_t*)&Ws[wn + j * 16 + m16][kk * 32 + quad * 8];
#pragma unroll
      for (int i = 0; i < 2; ++i)
#pragma unroll
        for (int j = 0; j < 2; ++j)
          acc[i][j] = __builtin_amdgcn_mfma_f32_16x16x32_bf16(aF[i], bF[j], acc[i][j], 0, 0, 0);
    }
    __syncthreads();
  }

  // epilogue: C/D layout col=lane&15, row=quad*4+reg
  if constexpr (OMODE == 2) {
    // stage bf16 into Ws transposed: Ws[n_local][m_local]
#pragma unroll
    for (int i = 0; i < 2; ++i)
#pragma unroll
      for (int r = 0; r < 4; ++r) {
        int ml = wm + i * 16 + quad * 4 + r;
#pragma unroll
        for (int j = 0; j < 2; ++j) {
          int nl = wn + j * 16 + m16;
          Ws[nl][ml] = f2bf(acc[i][j][r] + bias[bn + nl]);
        }
      }
    __syncthreads();
    int nl = tid >> 2, mc = (tid & 3) * 16;
    if (bm + mc < M) {  // M % 16 == 0 -> full chunk valid
      int n = bn + nl;
      __hip_bfloat16* dst = (__hip_bfloat16*)C +
          ((size_t)(n >> 5) * 32 + (n & 31)) * (size_t)M + bm + mc;
      *(short8_t*)dst = *(const short8_t*)&Ws[nl][mc];
      *(short8_t*)(dst + 8) = *(const short8_t*)&Ws[nl][mc + 8];
    }
  } else {
#pragma unroll
    for (int i = 0; i < 2; ++i) {
#pragma unroll
      for (int r = 0; r < 4; ++r) {
        int m = bm + wm + i * 16 + quad * 4 + r;
        if (m >= M) continue;
#pragma unroll
        for (int j = 0; j < 2; ++j) {
          int n = bn + wn + j * 16 + m16;
          float v = acc[i][j][r] + bias[n];
          if (EPI == 1) v = fmaxf(v, 0.f);
          if constexpr (OMODE == 1) {
            ((__hip_bfloat16*)C)[((size_t)(n >> 5) * M + m) * 32 + (n & 31)] = __float2bfloat16(v);
          } else if constexpr (__hip_internal::is_same<TOUT, float>::value) {
            C[(size_t)m * N + n] = v;
          } else {
            C[(size_t)m * N + n] = __float2bfloat16(v);
          }
        }
      }
    }
  }
}

// ---------------- flash attention, single wave per (hb, q-tile32, k-chunk) ----------------
// No-max softmax (scores O(1)): p = pred ? exp(s*scale) : 0. Partial O/L to scratch.
// S tiles key-interleaved: S-col n16 of tile0/1 <-> keys koff+2*n16, koff+2*n16+1.
// V is pre-transposed: Vt[h][dim][key] -> PV B-frag = 2 direct dwordx4 loads.
template<typename TQ, bool MASKED>
__global__ __launch_bounds__(64, 4) void attn_flash(
    const TQ* __restrict__ qb, size_t strQb, size_t strQh, int qRowStr,
    const __hip_bfloat16* __restrict__ kb, size_t strKb, size_t strKh, int kRowStr,
    const __hip_bfloat16* __restrict__ vt, size_t strVb, size_t strVh, size_t strVd,
    const unsigned* __restrict__ mT, size_t strMb,
    float* __restrict__ pO, size_t pStrO,
    float* __restrict__ pL, size_t pStrL,
    int nq, int nk, int kChunk) {
  int hb = blockIdx.x;
  int h = hb & 7, bz = hb >> 3;
  int qt = blockIdx.y, ks = blockIdx.z;
  int qbase = qt * 32;

  const TQ* q = qb + (size_t)bz * strQb + (size_t)h * strQh;
  const __hip_bfloat16* K = kb + (size_t)bz * strKb + (size_t)h * strKh;
  const __hip_bfloat16* V = vt + (size_t)bz * strVb + (size_t)h * strVh;
  const unsigned* mrow = MASKED ? (mT + (size_t)bz * strMb + (size_t)qt * cNK) : nullptr;

  int lane = threadIdx.x;
  int n16 = lane & 15, quad = lane >> 4;

  __shared__ short sP[32][40];  // 80 B rows (16B aligned)

  // Q A-frags
  short8_t qf[2];
#pragma unroll
  for (int qi = 0; qi < 2; ++qi) {
    qf[qi] = 0;
    int qr = qbase + qi * 16 + n16;
    if (qr < nq) {
      const TQ* qp = q + (size_t)qr * qRowStr + quad * 8;
      if constexpr (__hip_internal::is_same<TQ, float>::value) {
#pragma unroll
        for (int j = 0; j < 8; ++j) qf[qi][j] = f2bf(qp[j]);
      } else {
        qf[qi] = *(const short8_t*)qp;
      }
    }
  }
  short8_t ones;
#pragma unroll
  for (int j = 0; j < 8; ++j) ones[j] = f2bf(1.0f);

  float4_t accO[2][2], accL[2];
#pragma unroll
  for (int qi = 0; qi < 2; ++qi) {
    accL[qi] = (float4_t){0.f, 0.f, 0.f, 0.f};
#pragma unroll
    for (int di = 0; di < 2; ++di) accO[qi][di] = (float4_t){0.f, 0.f, 0.f, 0.f};
  }
  float4_t zero4 = {0.f, 0.f, 0.f, 0.f};

  int kbeg = ks * kChunk;
  int kend = kbeg + kChunk;
  if (kend > ((nk + 31) & ~31)) kend = (nk + 31) & ~31;
  for (int koff = kbeg; koff < kend; koff += 32) {
    int k0 = koff + 2 * n16;       // tile0 key for this lane's S-column
    // mask dwords (keys k0, k0+1)
    unsigned w0 = 0xFFFFFFFFu, w1 = 0xFFFFFFFFu;
    if (MASKED) {
      const unsigned* mp = mrow + k0;
      w0 = mp[0]; w1 = mp[1];
    }
    bool in0 = k0 < nk, in1 = (k0 + 1) < nk;
    // K B-frags (interleaved keys)
    short8_t kf0 = *(const short8_t*)(K + (size_t)k0 * kRowStr + quad * 8);
    short8_t kf1 = *(const short8_t*)(K + (size_t)(k0 + 1) * kRowStr + quad * 8);
    // Vt B-frags: dims n16 / 16+n16, keys koff+quad*8..+7 (contiguous)
    short8_t vf0 = *(const short8_t*)(V + (size_t)n16 * strVd + koff + quad * 8);
    short8_t vf1 = *(const short8_t*)(V + (size_t)(16 + n16) * strVd + koff + quad * 8);
    // S = Q.K^T
    float4_t s00 = __builtin_amdgcn_mfma_f32_16x16x32_bf16(qf[0], kf0, zero4, 0, 0, 0);
    float4_t s01 = __builtin_amdgcn_mfma_f32_16x16x32_bf16(qf[0], kf1, zero4, 0, 0, 0);
    float4_t s10 = __builtin_amdgcn_mfma_f32_16x16x32_bf16(qf[1], kf0, zero4, 0, 0, 0);
    float4_t s11 = __builtin_amdgcn_mfma_f32_16x16x32_bf16(qf[1], kf1, zero4, 0, 0, 0);
    // mask + exp -> P pairs packed as dword writes
#pragma unroll
    for (int qi = 0; qi < 2; ++qi) {
      const float4_t& sa = qi ? s10 : s00;
      const float4_t& sb = qi ? s11 : s01;
#pragma unroll
      for (int r = 0; r < 4; ++r) {
        int row = qi * 16 + quad * 4 + r;
        bool ok0 = in0, ok1 = in1;
        if (MASKED) {
          ok0 = ok0 && ((w0 >> row) & 1u);
          ok1 = ok1 && ((w1 >> row) & 1u);
        }
        float p0 = ok0 ? __expf(sa[r] * kScale) : 0.f;
        float p1 = ok1 ? __expf(sb[r] * kScale) : 0.f;
        unsigned pw = (unsigned)(unsigned short)f2bf(p0) |
                      ((unsigned)(unsigned short)f2bf(p1) << 16);
        *(unsigned*)&sP[row][2 * n16] = pw;
      }
    }
    // P A-frags (contiguous b128) + PV accumulate
#pragma unroll
    for (int qi = 0; qi < 2; ++qi) {
      short8_t pf = *(const short8_t*)&sP[qi * 16 + n16][quad * 8];
      accO[qi][0] = __builtin_amdgcn_mfma_f32_16x16x32_bf16(pf, vf0, accO[qi][0], 0, 0, 0);
      accO[qi][1] = __builtin_amdgcn_mfma_f32_16x16x32_bf16(pf, vf1, accO[qi][1], 0, 0, 0);
      accL[qi]    = __builtin_amdgcn_mfma_f32_16x16x32_bf16(pf, ones, accL[qi], 0, 0, 0);
    }
  }

  // write partials
  size_t oBase = (size_t)ks * pStrO + (size_t)(bz * cNQ) * 256 + h * 32;
  size_t lBase = (size_t)ks * pStrL + (size_t)hb * 320;
#pragma unroll
  for (int qi = 0; qi < 2; ++qi) {
#pragma unroll
    for (int r = 0; r < 4; ++r) {
      int row = qi * 16 + quad * 4 + r;
      if (qbase + row >= nq) continue;
#pragma unroll
      for (int di = 0; di < 2; ++di)
        pO[oBase + (size_t)(qbase + row) * 256 + di * 16 + n16] = accO[qi][di][r];
      if (n16 == 0) pL[lBase + qbase + row] = accL[qi][r];
    }
  }
}

// ---------------- merge k-split partials: out = sum(pO)/sum(pL) ----------------
__global__ __launch_bounds__(64) void attn_merge(const float* __restrict__ pO,
                                                 const float* __restrict__ pL,
                                                 float* __restrict__ out) {
  int row = blockIdx.x;            // 0..2399
  int lane = threadIdx.x;
  int c0 = lane * 4;
  int bz = row / cNQ, qq = row - bz * cNQ;
  int h = c0 >> 5;
  float l = 0.f;
#pragma unroll
  for (int ks = 0; ks < cKS; ++ks)
    l += pL[(size_t)ks * (64 * 320) + (size_t)(bz * 8 + h) * 320 + qq];
  float inv = 1.f / l;
  float o[4] = {0.f, 0.f, 0.f, 0.f};
#pragma unroll
  for (int ks = 0; ks < cKS; ++ks) {
    const float4_t v = *(const float4_t*)&pO[(size_t)ks * (MT * 256) + (size_t)row * 256 + c0];
#pragma unroll
    for (int u = 0; u < 4; ++u) o[u] += v[u];
  }
  float4_t res = {o[0] * inv, o[1] * inv, o[2] * inv, o[3] * inv};
  *(float4_t*)&out[(size_t)row * 256 + c0] = res;
}

// ---------------- residual + LayerNorm (in-place on t), one wave per row ----------------
__global__ __launch_bounds__(64) void add_ln_k(float* __restrict__ t, const float* __restrict__ delta,
                                               const float* __restrict__ g,
                                               const float* __restrict__ bb) {
  int r = blockIdx.x, lane = threadIdx.x;
  size_t base = (size_t)r * cE + lane * 4;
  float x[4];
  float s = 0.f;
#pragma unroll
  for (int i = 0; i < 4; ++i) { x[i] = t[base + i] + delta[base + i]; s += x[i]; }
  for (int off = 32; off; off >>= 1) s += __shfl_xor(s, off);
  float mean = s * (1.f / cE);
  float v = 0.f;
#pragma unroll
  for (int i = 0; i < 4; ++i) { float dd = x[i] - mean; v += dd * dd; }
  for (int off = 32; off; off >>= 1) v += __shfl_xor(v, off);
  float rstd = rsqrtf(v * (1.f / cE) + 1e-5f);
#pragma unroll
  for (int i = 0; i < 4; ++i)
    t[base + i] = (x[i] - mean) * rstd * g[lane * 4 + i] + bb[lane * 4 + i];
}

// ---------------- final LayerNorm -> fp32 out ----------------
__global__ __launch_bounds__(64) void final_ln_k(const float* __restrict__ t,
                                                 const float* __restrict__ g,
                                                 const float* __restrict__ bb,
                                                 float* __restrict__ out) {
  int r = blockIdx.x, lane = threadIdx.x;
  size_t base = (size_t)r * cE + lane * 4;
  float x[4];
  float s = 0.f;
#pragma unroll
  for (int i = 0; i < 4; ++i) { x[i] = t[base + i]; s += x[i]; }
  for (int off = 32; off; off >>= 1) s += __shfl_xor(s, off);
  float mean = s * (1.f / cE);
  float v = 0.f;
#pragma unroll
  for (int i = 0; i < 4; ++i) { float dd = x[i] - mean; v += dd * dd; }
  for (int off = 32; off; off >>= 1) v += __shfl_xor(v, off);
  float rstd = rsqrtf(v * (1.f / cE) + 1e-5f);
#pragma unroll
  for (int i = 0; i < 4; ++i)
    out[base + i] = (x[i] - mean) * rstd * g[lane * 4 + i] + bb[lane * 4 + i];
}

extern "C" void kernel_launch(void* const* d_in, const int* in_sizes, int n_in,
                              void* d_out, int out_size, void* d_ws, size_t ws_size,
                              hipStream_t stream) {
  (void)in_sizes; (void)n_in; (void)out_size;
  const float* tgt    = (const float*)d_in[0];
  const float* memory = (const float*)d_in[1];
  const int*   gmask  = (const int*)d_in[2];
  const float* w_in[8]  = {(const float*)d_in[3], (const float*)d_in[5], (const float*)d_in[7],
                           (const float*)d_in[9], (const float*)d_in[11], (const float*)d_in[13],
                           (const float*)d_in[15], (const float*)d_in[17]};
  const size_t w_sz[8]  = {(size_t)cL*3*cE*cE, (size_t)cL*cE*cE, (size_t)cL*cE*cE,
                           (size_t)cL*cE*cE, (size_t)cL*cE*cE, (size_t)cL*cE*cE,
                           (size_t)cL*cF*cE, (size_t)cL*cE*cF};
  const float* sa_bqkv = (const float*)d_in[4];
  const float* sa_bo   = (const float*)d_in[6];
  const float* ca_bq   = (const float*)d_in[8];
  const float* ca_bk   = (const float*)d_in[10];
  const float* ca_bv   = (const float*)d_in[12];
  const float* ca_bo   = (const float*)d_in[14];
  const float* f_b1    = (const float*)d_in[16];
  const float* f_b2    = (const float*)d_in[18];
  const float* ln1g = (const float*)d_in[19], *ln1b = (const float*)d_in[20];
  const float* ln2g = (const float*)d_in[21], *ln2b = (const float*)d_in[22];
  const float* ln3g = (const float*)d_in[23], *ln3b = (const float*)d_in[24];
  const float* lnfg = (const float*)d_in[25], *lnfb = (const float*)d_in[26];

  // ---- workspace allocator (256B aligned) ----
  char* wp = (char*)d_ws;
  auto alloc = [&](size_t bytes) { void* p = wp; wp += (bytes + 255) & ~(size_t)255; return p; };

  float* t  = (float*)alloc((size_t)MT * cE * 4);
  float* s1 = (float*)alloc((size_t)MT * cE * 4);           // also aliased as bf16 qbf
  float* s2 = (float*)alloc((size_t)MT * cE * 4);
  __hip_bfloat16* big2 = (__hip_bfloat16*)alloc((size_t)MT * 512 * 2);       // self Q|K
  __hip_bfloat16* vtq  = (__hip_bfloat16*)alloc((size_t)cH * cD * MT * 2);   // self Vt
  unsigned* mT = (unsigned*)alloc((size_t)cB * cQT * cNK * 4);
  float* pO = (float*)alloc((size_t)cKS * MT * 256 * 4);    // also aliased as ffnh (bf16)
  float* pL = (float*)alloc((size_t)cKS * 64 * 320 * 4);
  __hip_bfloat16* ffnh = (__hip_bfloat16*)pO;               // 9.83 MB alias (MT*cF*2 = 9.83 MB)
  __hip_bfloat16* wbf[8];
  for (int i = 0; i < 8; ++i) wbf[i] = (__hip_bfloat16*)alloc(w_sz[i] * 2);
  size_t mandatory = (size_t)(wp - (char*)d_ws);
  size_t kvFull = (size_t)cH * MM * cD * 2;                 // 16.78 MB each
  bool fullKV = ws_size >= mandatory + 2 * kvFull;
  __hip_bfloat16 *kbuf, *vtb;
  if (fullKV) {
    kbuf = (__hip_bfloat16*)alloc(kvFull);
    vtb  = (__hip_bfloat16*)alloc(kvFull);
  } else {
    kbuf = (__hip_bfloat16*)alloc((size_t)cH * cNK * cD * 2);
    vtb  = (__hip_bfloat16*)alloc((size_t)cH * cNK * cD * 2);
  }
  size_t memBytes = (size_t)MM * cE * 2;
  bool precast = ws_size >= (size_t)(wp - (char*)d_ws) + memBytes;
  __hip_bfloat16* membf = precast ? (__hip_bfloat16*)alloc(memBytes) : nullptr;

  // ---- one-time prep ----
  copy_f32<<<(MT * cE + 255) / 256, 256, 0, stream>>>(tgt, t, MT * cE);
  pack_mask_T<<<dim3(cNK / 256, cQT, cB), 256, 0, stream>>>(gmask, mT);
  for (int i = 0; i < 8; ++i)
    cast_f32_bf16<<<(int)((w_sz[i] + 255) / 256), 256, 0, stream>>>(w_in[i], wbf[i], (int)w_sz[i]);
  if (precast)
    cast_f32_bf16<<<(MM * cE + 255) / 256, 256, 0, stream>>>(memory, membf, MM * cE);

  const size_t pStrO = (size_t)MT * 256, pStrL = 64 * 320;

  for (int l = 0; l < cL; ++l) {
    const __hip_bfloat16* wqkv = wbf[0] + (size_t)l * 3 * cE * cE;
    const float* bqkv = sa_bqkv + (size_t)l * 3 * cE;
    const __hip_bfloat16* wo = wbf[1] + (size_t)l * cE * cE;  const float* bo = sa_bo + (size_t)l * cE;
    const __hip_bfloat16* wq = wbf[2] + (size_t)l * cE * cE;  const float* bq = ca_bq + (size_t)l * cE;
    const __hip_bfloat16* wk = wbf[3] + (size_t)l * cE * cE;  const float* bk = ca_bk + (size_t)l * cE;
    const __hip_bfloat16* wv = wbf[4] + (size_t)l * cE * cE;  const float* bv = ca_bv + (size_t)l * cE;
    const __hip_bfloat16* wco = wbf[5] + (size_t)l * cE * cE; const float* bco = ca_bo + (size_t)l * cE;
    const __hip_bfloat16* w1 = wbf[6] + (size_t)l * cF * cE;  const float* b1 = f_b1 + (size_t)l * cF;
    const __hip_bfloat16* w2 = wbf[7] + (size_t)l * cE * cF;  const float* b2 = f_b2 + (size_t)l * cE;

    // 1) self Q|K = t @ wqkv[0:512]^T -> big2 (bf16, stride 512)
    gemm_mfma<float, 0, 0, __hip_bfloat16><<<dim3(38, 8), 256, 0, stream>>>(
        t, wqkv, bqkv, big2, MT, 512, cE);
    // 2) self V^T = t @ wqkv[512:768]^T -> vtq [h][dim][2400]
    gemm_mfma<float, 0, 2, __hip_bfloat16><<<dim3(38, 4), 256, 0, stream>>>(
        t, wqkv + (size_t)512 * cE, bqkv + 512, vtq, MT, cE, cE);
    // 3) self flash (unmasked, k-split over 300 keys in chunks of 96)
    attn_flash<__hip_bfloat16, false><<<dim3(64, cQT, cKS), 64, 0, stream>>>(
        big2, (size_t)cNQ * 512, 32, 512,
        big2 + 256, (size_t)cNQ * 512, 32, 512,
        vtq, 300, (size_t)cD * MT, MT,
        nullptr, 0,
        pO, pStrO, pL, pStrL, cNQ, cNQ, 96);
    attn_merge<<<MT, 64, 0, stream>>>(pO, pL, s1);
    // 4) sa out proj -> s2
    gemm_mfma<float, 0, 0, float><<<dim3(38, 4), 256, 0, stream>>>(s1, wo, bo, s2, MT, cE, cE);
    add_ln_k<<<MT, 64, 0, stream>>>(t, s2, ln1g + (size_t)l * cE, ln1b + (size_t)l * cE);
    // 5) q proj -> qbf (bf16, aliases s1)
    __hip_bfloat16* qbf = (__hip_bfloat16*)s1;
    gemm_mfma<float, 0, 0, __hip_bfloat16><<<dim3(38, 4), 256, 0, stream>>>(
        t, wq, bq, qbf, MT, cE, cE);
    // 6) K head-major + V transposed + flash cross
    if (fullKV) {
      if (precast) {
        gemm_mfma<__hip_bfloat16, 0, 1, __hip_bfloat16><<<dim3(512, 4), 256, 0, stream>>>(
            membf, wk, bk, kbuf, MM, cE, cE);
        gemm_mfma<__hip_bfloat16, 0, 2, __hip_bfloat16><<<dim3(512, 4), 256, 0, stream>>>(
            membf, wv, bv, vtb, MM, cE, cE);
      } else {
        gemm_mfma<float, 0, 1, __hip_bfloat16><<<dim3(512, 4), 256, 0, stream>>>(
            memory, wk, bk, kbuf, MM, cE, cE);
        gemm_mfma<float, 0, 2, __hip_bfloat16><<<dim3(512, 4), 256, 0, stream>>>(
            memory, wv, bv, vtb, MM, cE, cE);
      }
      attn_flash<__hip_bfloat16, true><<<dim3(64, cQT, cKS), 64, 0, stream>>>(
          qbf, (size_t)cNQ * cE, 32, cE,
          kbuf, (size_t)cNK * cD, (size_t)MM * cD, cD,
          vtb, (size_t)cNK, (size_t)cD * MM, MM,
          mT, (size_t)cQT * cNK,
          pO, pStrO, pL, pStrL, cNQ, cNK, 1024);
      attn_merge<<<MT, 64, 0, stream>>>(pO, pL, s2);
    } else {
      for (int b = 0; b < cB; ++b) {
        const float* memb = memory + (size_t)b * cNK * cE;
        gemm_mfma<float, 0, 1, __hip_bfloat16><<<dim3(64, 4), 256, 0, stream>>>(
            memb, wk, bk, kbuf, cNK, cE, cE);
        gemm_mfma<float, 0, 2, __hip_bfloat16><<<dim3(64, 4), 256, 0, stream>>>(
            memb, wv, bv, vtb, cNK, cE, cE);
        attn_flash<__hip_bfloat16, true><<<dim3(8, cQT, cKS), 64, 0, stream>>>(
            qbf + (size_t)b * cNQ * cE, 0, 32, cE,
            kbuf, 0, (size_t)cNK * cD, cD,
            vtb, 0, (size_t)cD * cNK, cNK,
            mT + (size_t)b * cQT * cNK, 0,
            pO + (size_t)b * cNQ * 256, pStrO, pL + (size_t)b * 8 * 320, pStrL,
            cNQ, cNK, 1024);
      }
      attn_merge<<<MT, 64, 0, stream>>>(pO, pL, s2);
    }
    // 7) ca out proj -> s1 (fp32)
    gemm_mfma<float, 0, 0, float><<<dim3(38, 4), 256, 0, stream>>>(s2, wco, bco, s1, MT, cE, cE);
    add_ln_k<<<MT, 64, 0, stream>>>(t, s1, ln2g + (size_t)l * cE, ln2b + (size_t)l * cE);
    // 8) FFN: hidden = relu(t @ w1^T + b1) -> ffnh (bf16, aliases pO)
    gemm_mfma<float, 1, 0, __hip_bfloat16><<<dim3(38, 32), 256, 0, stream>>>(
        t, w1, b1, ffnh, MT, cF, cE);
    gemm_mfma<__hip_bfloat16, 0, 0, float><<<dim3(38, 4), 256, 0, stream>>>(
        ffnh, w2, b2, s1, MT, cE, cF);
    add_ln_k<<<MT, 64, 0, stream>>>(t, s1, ln3g + (size_t)l * cE, ln3b + (size_t)l * cE);
  }

  final_ln_k<<<MT, 64, 0, stream>>>(t, lnfg, lnfb, (float*)d_out);
}

// Round 9
// 1267.978 us; speedup vs baseline: 10.9686x; 1.2880x over previous
//
#include <hip/hip_runtime.h>
#include <hip/hip_bf16.h>

// Problem dims
constexpr int cB = 8, cNQ = 300, cNK = 4096, cE = 256, cH = 8, cD = 32, cF = 2048, cL = 6;
constexpr int MT = cB * cNQ;    // 2400 rows of target stream
constexpr int MM = cB * cNK;    // 32768 rows of memory stream
constexpr int cQT = 10;         // q-tiles of 32
constexpr int cKS = 4;          // k-split
constexpr float kScale = 0.17677669529663687f;  // 32^-0.5

typedef __attribute__((ext_vector_type(8))) short short8_t;
typedef __attribute__((ext_vector_type(4))) short short4_t;
typedef __attribute__((ext_vector_type(4))) float float4_t;

__device__ inline short f2bf(float x) {
  __hip_bfloat16 h = __float2bfloat16(x);
  return __builtin_bit_cast(short, h);
}

// ---------------- init t (fp32 + bf16 mirror) ----------------
__global__ void init_t(const float* __restrict__ in, float* __restrict__ t,
                       __hip_bfloat16* __restrict__ tb, int n) {
  int i = blockIdx.x * 256 + threadIdx.x;
  if (i < n) { float v = in[i]; t[i] = v; tb[i] = __float2bfloat16(v); }
}
__global__ void cast_f32_bf16(const float* __restrict__ in, __hip_bfloat16* __restrict__ out, int n) {
  int i = blockIdx.x * 256 + threadIdx.x;
  if (i < n) out[i] = __float2bfloat16(in[i]);
}

// ---------------- transposed mask pack: mT[b][qt][key], bit j = mask[b][qt*32+j][key] ----
__global__ void pack_mask_T(const int* __restrict__ m, unsigned* __restrict__ mT) {
  int key = blockIdx.x * 256 + threadIdx.x;
  int qt = blockIdx.y, b = blockIdx.z;
  unsigned w = 0;
  for (int j = 0; j < 32; ++j) {
    int q = qt * 32 + j;
    unsigned bit = (q < cNQ) ? (unsigned)(m[((size_t)b * cNQ + q) * cNK + key] != 0) : 0u;
    w |= bit << j;
  }
  mT[((size_t)b * cQT + qt) * cNK + key] = w;
}

// ---------------- 64x64 MFMA GEMM (small/medium grids) ----------------
// A: TA (float->cvt or bf16 direct). W: TW (float->cvt or bf16). fp32 accumulate.
// EPI 0/1(relu). OMODE 0 row-major / 1 K head-major / 2 V transposed.
template<typename TA, typename TW, int EPI, int OMODE, typename TOUT>
__global__ __launch_bounds__(256) void gemm_mfma(const TA* __restrict__ A,
                                                 const TW* __restrict__ W,
                                                 const float* __restrict__ bias,
                                                 TOUT* __restrict__ C,
                                                 int M, int N, int K) {
  constexpr int LDSS = 72;
  __shared__ short As[64][LDSS];
  __shared__ short Ws[64][LDSS];
  int tid = threadIdx.x;
  int bm = blockIdx.x * 64, bn = blockIdx.y * 64;
  int lane = tid & 63, wave = tid >> 6;
  int m16 = lane & 15, quad = lane >> 4;
  int wm = (wave >> 1) * 32, wn = (wave & 1) * 32;

  int srow = tid >> 2;
  int kc = (tid & 3) * 16;
  bool aok = (bm + srow) < M;

  float4_t acc[2][2];
#pragma unroll
  for (int i = 0; i < 2; ++i)
#pragma unroll
    for (int j = 0; j < 2; ++j) acc[i][j] = (float4_t){0.f, 0.f, 0.f, 0.f};

  for (int k0 = 0; k0 < K; k0 += 64) {
    if constexpr (__hip_internal::is_same<TA, float>::value) {
      const float* src = A + (size_t)(bm + srow) * K + k0 + kc;
      short8_t p0, p1;
#pragma unroll
      for (int u = 0; u < 8; ++u) p0[u] = aok ? f2bf(src[u]) : (short)0;
#pragma unroll
      for (int u = 0; u < 8; ++u) p1[u] = aok ? f2bf(src[8 + u]) : (short)0;
      *(short8_t*)&As[srow][kc] = p0;
      *(short8_t*)&As[srow][kc + 8] = p1;
    } else {
      const TA* src = A + (size_t)(bm + srow) * K + k0 + kc;
      short8_t z = 0;
      *(short8_t*)&As[srow][kc] = aok ? *(const short8_t*)src : z;
      *(short8_t*)&As[srow][kc + 8] = aok ? *(const short8_t*)(src + 8) : z;
    }
    if constexpr (__hip_internal::is_same<TW, float>::value) {
      const float* src = W + (size_t)(bn + srow) * K + k0 + kc;
      short8_t p0, p1;
#pragma unroll
      for (int u = 0; u < 8; ++u) p0[u] = f2bf(src[u]);
#pragma unroll
      for (int u = 0; u < 8; ++u) p1[u] = f2bf(src[8 + u]);
      *(short8_t*)&Ws[srow][kc] = p0;
      *(short8_t*)&Ws[srow][kc + 8] = p1;
    } else {
      const TW* src = W + (size_t)(bn + srow) * K + k0 + kc;
      *(short8_t*)&Ws[srow][kc] = *(const short8_t*)src;
      *(short8_t*)&Ws[srow][kc + 8] = *(const short8_t*)(src + 8);
    }
    __syncthreads();
#pragma unroll
    for (int kk = 0; kk < 2; ++kk) {
      short8_t aF[2], bF[2];
#pragma unroll
      for (int i = 0; i < 2; ++i)
        aF[i] = *(const short8_t*)&As[wm + i * 16 + m16][kk * 32 + quad * 8];
#pragma unroll
      for (int j = 0; j < 2; ++j)
        bF[j] = *(const short8_t*)&Ws[wn + j * 16 + m16][kk * 32 + quad * 8];
#pragma unroll
      for (int i = 0; i < 2; ++i)
#pragma unroll
        for (int j = 0; j < 2; ++j)
          acc[i][j] = __builtin_amdgcn_mfma_f32_16x16x32_bf16(aF[i], bF[j], acc[i][j], 0, 0, 0);
    }
    __syncthreads();
  }

  if constexpr (OMODE == 2) {
#pragma unroll
    for (int i = 0; i < 2; ++i)
#pragma unroll
      for (int r = 0; r < 4; ++r) {
        int ml = wm + i * 16 + quad * 4 + r;
#pragma unroll
        for (int j = 0; j < 2; ++j) {
          int nl = wn + j * 16 + m16;
          Ws[nl][ml] = f2bf(acc[i][j][r] + bias[bn + nl]);
        }
      }
    __syncthreads();
    int nl = tid >> 2, mc = (tid & 3) * 16;
    if (bm + mc < M) {
      int n = bn + nl;
      __hip_bfloat16* dst = (__hip_bfloat16*)C +
          ((size_t)(n >> 5) * 32 + (n & 31)) * (size_t)M + bm + mc;
      *(short8_t*)dst = *(const short8_t*)&Ws[nl][mc];
      *(short8_t*)(dst + 8) = *(const short8_t*)&Ws[nl][mc + 8];
    }
  } else {
#pragma unroll
    for (int i = 0; i < 2; ++i) {
#pragma unroll
      for (int r = 0; r < 4; ++r) {
        int m = bm + wm + i * 16 + quad * 4 + r;
        if (m >= M) continue;
#pragma unroll
        for (int j = 0; j < 2; ++j) {
          int n = bn + wn + j * 16 + m16;
          float v = acc[i][j][r] + bias[n];
          if (EPI == 1) v = fmaxf(v, 0.f);
          if constexpr (OMODE == 1) {
            ((__hip_bfloat16*)C)[((size_t)(n >> 5) * M + m) * 32 + (n & 31)] = __float2bfloat16(v);
          } else if constexpr (__hip_internal::is_same<TOUT, float>::value) {
            C[(size_t)m * N + n] = v;
          } else {
            C[(size_t)m * N + n] = __float2bfloat16(v);
          }
        }
      }
    }
  }
}

// ---------------- 128x128 MFMA GEMM (big grids: K/V proj, FFN-w1) ----------------
// A bf16. W: TW. 4 waves, each 64x64 via 4x4 mfma_16x16x32. BK=64. LDS 36 KB.
template<typename TW, int EPI, int OMODE, typename TOUT>
__global__ __launch_bounds__(256) void gemm128(const __hip_bfloat16* __restrict__ A,
                                               const TW* __restrict__ W,
                                               const float* __restrict__ bias,
                                               TOUT* __restrict__ C,
                                               int M, int N, int K) {
  __shared__ short lds[2 * 128 * 72];
  auto As = (short(*)[72])lds;
  auto Ws = (short(*)[72])(lds + 128 * 72);
  int tid = threadIdx.x;
  int bm = blockIdx.x * 128, bn = blockIdx.y * 128;
  int lane = tid & 63, wave = tid >> 6;
  int n16 = lane & 15, quad = lane >> 4;
  int wm = (wave >> 1) * 64, wn = (wave & 1) * 64;
  int srow = tid >> 1, kc = (tid & 1) * 32;
  bool aok = (bm + srow) < M;

  float4_t acc[4][4];
#pragma unroll
  for (int i = 0; i < 4; ++i)
#pragma unroll
    for (int j = 0; j < 4; ++j) acc[i][j] = (float4_t){0.f, 0.f, 0.f, 0.f};

  for (int k0 = 0; k0 < K; k0 += 64) {
    {
      const __hip_bfloat16* src = A + (size_t)(bm + srow) * K + k0 + kc;
      short8_t z = 0;
#pragma unroll
      for (int u = 0; u < 4; ++u)
        *(short8_t*)&As[srow][kc + u * 8] = aok ? *(const short8_t*)(src + u * 8) : z;
    }
    if constexpr (__hip_internal::is_same<TW, float>::value) {
      const float* src = W + (size_t)(bn + srow) * K + k0 + kc;
#pragma unroll
      for (int u = 0; u < 4; ++u) {
        short8_t p;
#pragma unroll
        for (int v = 0; v < 8; ++v) p[v] = f2bf(src[u * 8 + v]);
        *(short8_t*)&Ws[srow][kc + u * 8] = p;
      }
    } else {
      const TW* src = W + (size_t)(bn + srow) * K + k0 + kc;
#pragma unroll
      for (int u = 0; u < 4; ++u)
        *(short8_t*)&Ws[srow][kc + u * 8] = *(const short8_t*)(src + u * 8);
    }
    __syncthreads();
#pragma unroll
    for (int kk = 0; kk < 2; ++kk) {
      short8_t aF[4], bF[4];
#pragma unroll
      for (int i = 0; i < 4; ++i)
        aF[i] = *(const short8_t*)&As[wm + i * 16 + n16][kk * 32 + quad * 8];
#pragma unroll
      for (int j = 0; j < 4; ++j)
        bF[j] = *(const short8_t*)&Ws[wn + j * 16 + n16][kk * 32 + quad * 8];
#pragma unroll
      for (int i = 0; i < 4; ++i)
#pragma unroll
        for (int j = 0; j < 4; ++j)
          acc[i][j] = __builtin_amdgcn_mfma_f32_16x16x32_bf16(aF[i], bF[j], acc[i][j], 0, 0, 0);
    }
    __syncthreads();
  }

  if constexpr (OMODE == 2) {
    // transpose via LDS: TT[n_local][m_local]
    auto TT = (short(*)[128])lds;
#pragma unroll
    for (int i = 0; i < 4; ++i)
#pragma unroll
      for (int r = 0; r < 4; ++r) {
        int ml = wm + i * 16 + quad * 4 + r;
#pragma unroll
        for (int j = 0; j < 4; ++j) {
          int nl = wn + j * 16 + n16;
          TT[nl][ml] = f2bf(acc[i][j][r] + bias[bn + nl]);
        }
      }
    __syncthreads();
    int nl = tid >> 1, mh = (tid & 1) * 64;
    int n = bn + nl;
    __hip_bfloat16* dst = (__hip_bfloat16*)C +
        ((size_t)(n >> 5) * 32 + (n & 31)) * (size_t)M + bm + mh;
#pragma unroll
    for (int ch = 0; ch < 8; ++ch) {
      if (bm + mh + ch * 8 < M)
        *(short8_t*)(dst + ch * 8) = *(const short8_t*)&TT[nl][mh + ch * 8];
    }
  } else {
#pragma unroll
    for (int i = 0; i < 4; ++i) {
#pragma unroll
      for (int r = 0; r < 4; ++r) {
        int m = bm + wm + i * 16 + quad * 4 + r;
        if (m >= M) continue;
#pragma unroll
        for (int j = 0; j < 4; ++j) {
          int n = bn + wn + j * 16 + n16;
          float v = acc[i][j][r] + bias[n];
          if (EPI == 1) v = fmaxf(v, 0.f);
          if constexpr (OMODE == 1) {
            ((__hip_bfloat16*)C)[((size_t)(n >> 5) * M + m) * 32 + (n & 31)] = __float2bfloat16(v);
          } else if constexpr (__hip_internal::is_same<TOUT, float>::value) {
            C[(size_t)m * N + n] = v;
          } else {
            C[(size_t)m * N + n] = __float2bfloat16(v);
          }
        }
      }
    }
  }
}

// ---------------- flash attention, single wave per (hb, q-tile32, k-chunk) ----------------
template<typename TQ, bool MASKED>
__global__ __launch_bounds__(64, 4) void attn_flash(
    const TQ* __restrict__ qb, size_t strQb, size_t strQh, int qRowStr,
    const __hip_bfloat16* __restrict__ kb, size_t strKb, size_t strKh, int kRowStr,
    const __hip_bfloat16* __restrict__ vt, size_t strVb, size_t strVh, size_t strVd,
    const unsigned* __restrict__ mT, size_t strMb,
    float* __restrict__ pO, size_t pStrO,
    float* __restrict__ pL, size_t pStrL,
    int nq, int nk, int kChunk) {
  int hb = blockIdx.x;
  int h = hb & 7, bz = hb >> 3;
  int qt = blockIdx.y, ks = blockIdx.z;
  int qbase = qt * 32;

  const TQ* q = qb + (size_t)bz * strQb + (size_t)h * strQh;
  const __hip_bfloat16* K = kb + (size_t)bz * strKb + (size_t)h * strKh;
  const __hip_bfloat16* V = vt + (size_t)bz * strVb + (size_t)h * strVh;
  const unsigned* mrow = MASKED ? (mT + (size_t)bz * strMb + (size_t)qt * cNK) : nullptr;

  int lane = threadIdx.x;
  int n16 = lane & 15, quad = lane >> 4;

  __shared__ short sP[32][40];

  short8_t qf[2];
#pragma unroll
  for (int qi = 0; qi < 2; ++qi) {
    qf[qi] = 0;
    int qr = qbase + qi * 16 + n16;
    if (qr < nq) {
      const TQ* qp = q + (size_t)qr * qRowStr + quad * 8;
      if constexpr (__hip_internal::is_same<TQ, float>::value) {
#pragma unroll
        for (int j = 0; j < 8; ++j) qf[qi][j] = f2bf(qp[j]);
      } else {
        qf[qi] = *(const short8_t*)qp;
      }
    }
  }
  short8_t ones;
#pragma unroll
  for (int j = 0; j < 8; ++j) ones[j] = f2bf(1.0f);

  float4_t accO[2][2], accL[2];
#pragma unroll
  for (int qi = 0; qi < 2; ++qi) {
    accL[qi] = (float4_t){0.f, 0.f, 0.f, 0.f};
#pragma unroll
    for (int di = 0; di < 2; ++di) accO[qi][di] = (float4_t){0.f, 0.f, 0.f, 0.f};
  }
  float4_t zero4 = {0.f, 0.f, 0.f, 0.f};

  int kbeg = ks * kChunk;
  int kend = kbeg + kChunk;
  if (kend > ((nk + 31) & ~31)) kend = (nk + 31) & ~31;
  for (int koff = kbeg; koff < kend; koff += 32) {
    int k0 = koff + 2 * n16;
    unsigned w0 = 0xFFFFFFFFu, w1 = 0xFFFFFFFFu;
    if (MASKED) {
      const unsigned* mp = mrow + k0;
      w0 = mp[0]; w1 = mp[1];
    }
    bool in0 = k0 < nk, in1 = (k0 + 1) < nk;
    short8_t kf0 = *(const short8_t*)(K + (size_t)k0 * kRowStr + quad * 8);
    short8_t kf1 = *(const short8_t*)(K + (size_t)(k0 + 1) * kRowStr + quad * 8);
    short8_t vf0 = *(const short8_t*)(V + (size_t)n16 * strVd + koff + quad * 8);
    short8_t vf1 = *(const short8_t*)(V + (size_t)(16 + n16) * strVd + koff + quad * 8);
    float4_t s00 = __builtin_amdgcn_mfma_f32_16x16x32_bf16(qf[0], kf0, zero4, 0, 0, 0);
    float4_t s01 = __builtin_amdgcn_mfma_f32_16x16x32_bf16(qf[0], kf1, zero4, 0, 0, 0);
    float4_t s10 = __builtin_amdgcn_mfma_f32_16x16x32_bf16(qf[1], kf0, zero4, 0, 0, 0);
    float4_t s11 = __builtin_amdgcn_mfma_f32_16x16x32_bf16(qf[1], kf1, zero4, 0, 0, 0);
#pragma unroll
    for (int qi = 0; qi < 2; ++qi) {
      const float4_t& sa = qi ? s10 : s00;
      const float4_t& sb = qi ? s11 : s01;
#pragma unroll
      for (int r = 0; r < 4; ++r) {
        int row = qi * 16 + quad * 4 + r;
        bool ok0 = in0, ok1 = in1;
        if (MASKED) {
          ok0 = ok0 && ((w0 >> row) & 1u);
          ok1 = ok1 && ((w1 >> row) & 1u);
        }
        float p0 = ok0 ? __expf(sa[r] * kScale) : 0.f;
        float p1 = ok1 ? __expf(sb[r] * kScale) : 0.f;
        unsigned pw = (unsigned)(unsigned short)f2bf(p0) |
                      ((unsigned)(unsigned short)f2bf(p1) << 16);
        *(unsigned*)&sP[row][2 * n16] = pw;
      }
    }
#pragma unroll
    for (int qi = 0; qi < 2; ++qi) {
      short8_t pf = *(const short8_t*)&sP[qi * 16 + n16][quad * 8];
      accO[qi][0] = __builtin_amdgcn_mfma_f32_16x16x32_bf16(pf, vf0, accO[qi][0], 0, 0, 0);
      accO[qi][1] = __builtin_amdgcn_mfma_f32_16x16x32_bf16(pf, vf1, accO[qi][1], 0, 0, 0);
      accL[qi]    = __builtin_amdgcn_mfma_f32_16x16x32_bf16(pf, ones, accL[qi], 0, 0, 0);
    }
  }

  size_t oBase = (size_t)ks * pStrO + (size_t)(bz * cNQ) * 256 + h * 32;
  size_t lBase = (size_t)ks * pStrL + (size_t)hb * 320;
#pragma unroll
  for (int qi = 0; qi < 2; ++qi) {
#pragma unroll
    for (int r = 0; r < 4; ++r) {
      int row = qi * 16 + quad * 4 + r;
      if (qbase + row >= nq) continue;
#pragma unroll
      for (int di = 0; di < 2; ++di)
        pO[oBase + (size_t)(qbase + row) * 256 + di * 16 + n16] = accO[qi][di][r];
      if (n16 == 0) pL[lBase + qbase + row] = accL[qi][r];
    }
  }
}

// ---------------- merge k-split partials -> bf16 ----------------
__global__ __launch_bounds__(64) void attn_merge(const float* __restrict__ pO,
                                                 const float* __restrict__ pL,
                                                 __hip_bfloat16* __restrict__ out) {
  int row = blockIdx.x;
  int lane = threadIdx.x;
  int c0 = lane * 4;
  int bz = row / cNQ, qq = row - bz * cNQ;
  int h = c0 >> 5;
  float l = 0.f;
#pragma unroll
  for (int ks = 0; ks < cKS; ++ks)
    l += pL[(size_t)ks * (64 * 320) + (size_t)(bz * 8 + h) * 320 + qq];
  float inv = 1.f / l;
  float o[4] = {0.f, 0.f, 0.f, 0.f};
#pragma unroll
  for (int ks = 0; ks < cKS; ++ks) {
    const float4_t v = *(const float4_t*)&pO[(size_t)ks * (MT * 256) + (size_t)row * 256 + c0];
#pragma unroll
    for (int u = 0; u < 4; ++u) o[u] += v[u];
  }
  short4_t res = {f2bf(o[0] * inv), f2bf(o[1] * inv), f2bf(o[2] * inv), f2bf(o[3] * inv)};
  *(short4_t*)&out[(size_t)row * 256 + c0] = res;
}

// ---------------- residual + LayerNorm (fp32 t + bf16 mirror), one wave per row ------
__global__ __launch_bounds__(64) void add_ln_k(float* __restrict__ t,
                                               __hip_bfloat16* __restrict__ tb,
                                               const float* __restrict__ delta,
                                               const float* __restrict__ g,
                                               const float* __restrict__ bb) {
  int r = blockIdx.x, lane = threadIdx.x;
  size_t base = (size_t)r * cE + lane * 4;
  float x[4];
  float s = 0.f;
#pragma unroll
  for (int i = 0; i < 4; ++i) { x[i] = t[base + i] + delta[base + i]; s += x[i]; }
  for (int off = 32; off; off >>= 1) s += __shfl_xor(s, off);
  float mean = s * (1.f / cE);
  float v = 0.f;
#pragma unroll
  for (int i = 0; i < 4; ++i) { float dd = x[i] - mean; v += dd * dd; }
  for (int off = 32; off; off >>= 1) v += __shfl_xor(v, off);
  float rstd = rsqrtf(v * (1.f / cE) + 1e-5f);
  float y[4];
#pragma unroll
  for (int i = 0; i < 4; ++i) {
    y[i] = (x[i] - mean) * rstd * g[lane * 4 + i] + bb[lane * 4 + i];
    t[base + i] = y[i];
  }
  short4_t pb = {f2bf(y[0]), f2bf(y[1]), f2bf(y[2]), f2bf(y[3])};
  *(short4_t*)&tb[base] = pb;
}

// ---------------- final LayerNorm -> fp32 out ----------------
__global__ __launch_bounds__(64) void final_ln_k(const float* __restrict__ t,
                                                 const float* __restrict__ g,
                                                 const float* __restrict__ bb,
                                                 float* __restrict__ out) {
  int r = blockIdx.x, lane = threadIdx.x;
  size_t base = (size_t)r * cE + lane * 4;
  float x[4];
  float s = 0.f;
#pragma unroll
  for (int i = 0; i < 4; ++i) { x[i] = t[base + i]; s += x[i]; }
  for (int off = 32; off; off >>= 1) s += __shfl_xor(s, off);
  float mean = s * (1.f / cE);
  float v = 0.f;
#pragma unroll
  for (int i = 0; i < 4; ++i) { float dd = x[i] - mean; v += dd * dd; }
  for (int off = 32; off; off >>= 1) v += __shfl_xor(v, off);
  float rstd = rsqrtf(v * (1.f / cE) + 1e-5f);
#pragma unroll
  for (int i = 0; i < 4; ++i)
    out[base + i] = (x[i] - mean) * rstd * g[lane * 4 + i] + bb[lane * 4 + i];
}

// ---------------- pipeline (templated on weight dtype TW) ----------------
struct Bufs {
  float *t, *s1, *s2, *pO, *pL;
  __hip_bfloat16 *tb, *big2, *vtq, *s1b, *s2b, *qbf, *ffnh, *kbuf, *vtb, *membf;
  unsigned* mTr;
  const float* memory;
  bool fullKV, precast;
};

template<typename TW>
static void run_layers(const TW* const* wt, const float* const* bs,
                       const float* ln1g, const float* ln1b,
                       const float* ln2g, const float* ln2b,
                       const float* ln3g, const float* ln3b,
                       Bufs B, hipStream_t stream) {
  const size_t pStrO = (size_t)MT * 256, pStrL = 64 * 320;
  for (int l = 0; l < cL; ++l) {
    const TW* wqkv = wt[0] + (size_t)l * 3 * cE * cE;  const float* bqkv = bs[0] + (size_t)l * 3 * cE;
    const TW* wo   = wt[1] + (size_t)l * cE * cE;      const float* bo   = bs[1] + (size_t)l * cE;
    const TW* wq   = wt[2] + (size_t)l * cE * cE;      const float* bq   = bs[2] + (size_t)l * cE;
    const TW* wk   = wt[3] + (size_t)l * cE * cE;      const float* bk   = bs[3] + (size_t)l * cE;
    const TW* wv   = wt[4] + (size_t)l * cE * cE;      const float* bv   = bs[4] + (size_t)l * cE;
    const TW* wco  = wt[5] + (size_t)l * cE * cE;      const float* bco  = bs[5] + (size_t)l * cE;
    const TW* w1   = wt[6] + (size_t)l * cF * cE;      const float* b1   = bs[6] + (size_t)l * cF;
    const TW* w2   = wt[7] + (size_t)l * cE * cF;      const float* b2   = bs[7] + (size_t)l * cE;

    // 1) self Q|K -> big2 (bf16, stride 512)
    gemm_mfma<__hip_bfloat16, TW, 0, 0, __hip_bfloat16><<<dim3(38, 8), 256, 0, stream>>>(
        B.tb, wqkv, bqkv, B.big2, MT, 512, cE);
    // 2) self V^T -> vtq [h][dim][2400]
    gemm_mfma<__hip_bfloat16, TW, 0, 2, __hip_bfloat16><<<dim3(38, 4), 256, 0, stream>>>(
        B.tb, wqkv + (size_t)512 * cE, bqkv + 512, B.vtq, MT, cE, cE);
    // 3) self flash + merge -> s1b
    attn_flash<__hip_bfloat16, false><<<dim3(64, cQT, cKS), 64, 0, stream>>>(
        B.big2, (size_t)cNQ * 512, 32, 512,
        B.big2 + 256, (size_t)cNQ * 512, 32, 512,
        B.vtq, 300, (size_t)cD * MT, MT,
        nullptr, 0,
        B.pO, pStrO, B.pL, pStrL, cNQ, cNQ, 96);
    attn_merge<<<MT, 64, 0, stream>>>(B.pO, B.pL, B.s1b);
    // 4) sa out proj -> s2 (fp32)
    gemm_mfma<__hip_bfloat16, TW, 0, 0, float><<<dim3(38, 4), 256, 0, stream>>>(
        B.s1b, wo, bo, B.s2, MT, cE, cE);
    add_ln_k<<<MT, 64, 0, stream>>>(B.t, B.tb, B.s2, ln1g + (size_t)l * cE, ln1b + (size_t)l * cE);
    // 5) q proj -> qbf
    gemm_mfma<__hip_bfloat16, TW, 0, 0, __hip_bfloat16><<<dim3(38, 4), 256, 0, stream>>>(
        B.tb, wq, bq, B.qbf, MT, cE, cE);
    // 6) K/V projections + cross flash
    if (B.fullKV && B.precast) {
      gemm128<TW, 0, 1, __hip_bfloat16><<<dim3(256, 2), 256, 0, stream>>>(
          B.membf, wk, bk, B.kbuf, MM, cE, cE);
      gemm128<TW, 0, 2, __hip_bfloat16><<<dim3(256, 2), 256, 0, stream>>>(
          B.membf, wv, bv, B.vtb, MM, cE, cE);
      attn_flash<__hip_bfloat16, true><<<dim3(64, cQT, cKS), 64, 0, stream>>>(
          B.qbf, (size_t)cNQ * cE, 32, cE,
          B.kbuf, (size_t)cNK * cD, (size_t)MM * cD, cD,
          B.vtb, (size_t)cNK, (size_t)cD * MM, MM,
          B.mTr, (size_t)cQT * cNK,
          B.pO, pStrO, B.pL, pStrL, cNQ, cNK, 1024);
      attn_merge<<<MT, 64, 0, stream>>>(B.pO, B.pL, B.s2b);
    } else {
      for (int b = 0; b < cB; ++b) {
        const float* memb = B.memory + (size_t)b * cNK * cE;
        gemm_mfma<float, TW, 0, 1, __hip_bfloat16><<<dim3(64, 4), 256, 0, stream>>>(
            memb, wk, bk, B.kbuf, cNK, cE, cE);
        gemm_mfma<float, TW, 0, 2, __hip_bfloat16><<<dim3(64, 4), 256, 0, stream>>>(
            memb, wv, bv, B.vtb, cNK, cE, cE);
        attn_flash<__hip_bfloat16, true><<<dim3(8, cQT, cKS), 64, 0, stream>>>(
            B.qbf + (size_t)b * cNQ * cE, 0, 32, cE,
            B.kbuf, 0, (size_t)cNK * cD, cD,
            B.vtb, 0, (size_t)cD * cNK, cNK,
            B.mTr + (size_t)b * cQT * cNK, 0,
            B.pO + (size_t)b * cNQ * 256, pStrO, B.pL + (size_t)b * 8 * 320, pStrL,
            cNQ, cNK, 1024);
      }
      attn_merge<<<MT, 64, 0, stream>>>(B.pO, B.pL, B.s2b);
    }
    // 7) ca out proj -> s1 (fp32)
    gemm_mfma<__hip_bfloat16, TW, 0, 0, float><<<dim3(38, 4), 256, 0, stream>>>(
        B.s2b, wco, bco, B.s1, MT, cE, cE);
    add_ln_k<<<MT, 64, 0, stream>>>(B.t, B.tb, B.s1, ln2g + (size_t)l * cE, ln2b + (size_t)l * cE);
    // 8) FFN
    gemm128<TW, 1, 0, __hip_bfloat16><<<dim3(19, 16), 256, 0, stream>>>(
        B.tb, w1, b1, B.ffnh, MT, cF, cE);
    gemm_mfma<__hip_bfloat16, TW, 0, 0, float><<<dim3(38, 4), 256, 0, stream>>>(
        B.ffnh, w2, b2, B.s1, MT, cE, cF);
    add_ln_k<<<MT, 64, 0, stream>>>(B.t, B.tb, B.s1, ln3g + (size_t)l * cE, ln3b + (size_t)l * cE);
  }
}

extern "C" void kernel_launch(void* const* d_in, const int* in_sizes, int n_in,
                              void* d_out, int out_size, void* d_ws, size_t ws_size,
                              hipStream_t stream) {
  (void)in_sizes; (void)n_in; (void)out_size;
  const float* tgt    = (const float*)d_in[0];
  const float* memory = (const float*)d_in[1];
  const int*   gmask  = (const int*)d_in[2];
  const float* w_in[8]  = {(const float*)d_in[3], (const float*)d_in[5], (const float*)d_in[7],
                           (const float*)d_in[9], (const float*)d_in[11], (const float*)d_in[13],
                           (const float*)d_in[15], (const float*)d_in[17]};
  const float* b_in[8]  = {(const float*)d_in[4], (const float*)d_in[6], (const float*)d_in[8],
                           (const float*)d_in[10], (const float*)d_in[12], (const float*)d_in[14],
                           (const float*)d_in[16], (const float*)d_in[18]};
  const size_t w_sz[8]  = {(size_t)cL*3*cE*cE, (size_t)cL*cE*cE, (size_t)cL*cE*cE,
                           (size_t)cL*cE*cE, (size_t)cL*cE*cE, (size_t)cL*cE*cE,
                           (size_t)cL*cF*cE, (size_t)cL*cE*cF};
  const float* ln1g = (const float*)d_in[19], *ln1b = (const float*)d_in[20];
  const float* ln2g = (const float*)d_in[21], *ln2b = (const float*)d_in[22];
  const float* ln3g = (const float*)d_in[23], *ln3b = (const float*)d_in[24];
  const float* lnfg = (const float*)d_in[25], *lnfb = (const float*)d_in[26];

  // ---- workspace allocator (256B aligned), ordered by value ----
  char* wp = (char*)d_ws;
  auto alloc = [&](size_t bytes) { void* p = wp; wp += (bytes + 255) & ~(size_t)255; return p; };

  Bufs B;
  B.memory = memory;
  B.t  = (float*)alloc((size_t)MT * cE * 4);
  B.s1 = (float*)alloc((size_t)MT * cE * 4);
  B.s2 = (float*)alloc((size_t)MT * cE * 4);
  B.tb = (__hip_bfloat16*)alloc((size_t)MT * cE * 2);
  B.big2 = (__hip_bfloat16*)alloc((size_t)MT * 512 * 2);
  B.vtq  = (__hip_bfloat16*)alloc((size_t)cH * cD * MT * 2);
  B.mTr = (unsigned*)alloc((size_t)cB * cQT * cNK * 4);
  B.pO = (float*)alloc((size_t)cKS * MT * 256 * 4);
  B.pL = (float*)alloc((size_t)cKS * 64 * 320 * 4);
  B.s1b = B.big2;                                  // alias (big2 free after self-flash)
  B.s2b = B.big2 + (size_t)MT * 256;               // alias (upper half)
  B.qbf = (__hip_bfloat16*)B.s1;                   // alias (s1 fp32 written later)
  B.ffnh = (__hip_bfloat16*)B.pO;                  // alias (pO free during FFN)

  size_t kvFull = (size_t)cH * MM * cD * 2;        // 16.78 MB each
  size_t used = (size_t)(wp - (char*)d_ws);
  B.fullKV = ws_size >= used + 2 * kvFull;
  if (B.fullKV) {
    B.kbuf = (__hip_bfloat16*)alloc(kvFull);
    B.vtb  = (__hip_bfloat16*)alloc(kvFull);
  } else {
    B.kbuf = (__hip_bfloat16*)alloc((size_t)cH * cNK * cD * 2);
    B.vtb  = (__hip_bfloat16*)alloc((size_t)cH * cNK * cD * 2);
  }
  size_t memBytes = (size_t)MM * cE * 2;
  used = (size_t)(wp - (char*)d_ws);
  B.precast = B.fullKV && (ws_size >= used + memBytes);
  B.membf = B.precast ? (__hip_bfloat16*)alloc(memBytes) : nullptr;

  size_t wbfTotal = 0;
  for (int i = 0; i < 8; ++i) wbfTotal += ((w_sz[i] * 2 + 255) & ~(size_t)255);
  used = (size_t)(wp - (char*)d_ws);
  bool wPre = ws_size >= used + wbfTotal;
  __hip_bfloat16* wbf[8] = {};
  if (wPre)
    for (int i = 0; i < 8; ++i) wbf[i] = (__hip_bfloat16*)alloc(w_sz[i] * 2);

  // ---- one-time prep ----
  init_t<<<(MT * cE + 255) / 256, 256, 0, stream>>>(tgt, B.t, B.tb, MT * cE);
  pack_mask_T<<<dim3(cNK / 256, cQT, cB), 256, 0, stream>>>(gmask, B.mTr);
  if (B.precast)
    cast_f32_bf16<<<(MM * cE + 255) / 256, 256, 0, stream>>>(memory, B.membf, MM * cE);
  if (wPre)
    for (int i = 0; i < 8; ++i)
      cast_f32_bf16<<<(int)((w_sz[i] + 255) / 256), 256, 0, stream>>>(w_in[i], wbf[i], (int)w_sz[i]);

  if (wPre) {
    const __hip_bfloat16* wt[8];
    for (int i = 0; i < 8; ++i) wt[i] = wbf[i];
    run_layers<__hip_bfloat16>(wt, b_in, ln1g, ln1b, ln2g, ln2b, ln3g, ln3b, B, stream);
  } else {
    run_layers<float>(w_in, b_in, ln1g, ln1b, ln2g, ln2b, ln3g, ln3b, B, stream);
  }

  final_ln_k<<<MT, 64, 0, stream>>>(B.t, lnfg, lnfb, (float*)d_out);
}